// Round 12
// baseline (246.148 us; speedup 1.0000x reference)
//
#include <hip/hip_runtime.h>

#define F0 11
#define F1 64
#define F2 128
#define TN2 128      // nodes per block in k_gemm2

#define CHUNKS 64
#define BPR 12544    // bins per range; 12544%64==0; supports N <= 8*BPR = 100352 (src fits 17 bits)
#define WPR (BPR / 2)
#define NBKT (CHUNKS * 8 * 4)
#define NN1 64       // nodes per block in edge-parallel agg kernels

// bf16 helpers (round-to-nearest-even)
__device__ __forceinline__ unsigned short f2bf(float v) {
  unsigned u = __float_as_uint(v);
  unsigned r = u + 0x7FFFu + ((u >> 16) & 1u);
  return (unsigned short)(r >> 16);
}
__device__ __forceinline__ float bf2f(unsigned short s) {
  return __uint_as_float(((unsigned)s) << 16);
}
__device__ __forceinline__ float bf2f_lo(unsigned v) { return __uint_as_float(v << 16); }
__device__ __forceinline__ float bf2f_hi(unsigned v) { return __uint_as_float(v & 0xFFFF0000u); }

// ---------------- pad x (11 fp32) -> x16b (16 bf16 per row) ----------------
__global__ void k_pad(const float* __restrict__ x, unsigned short* __restrict__ x16b, int n) {
  int i = blockIdx.x * blockDim.x + threadIdx.x;
  if (i >= n * 16) return;
  int r = i >> 4, f = i & 15;
  x16b[i] = (f < F0) ? f2bf(x[(size_t)r * F0 + f]) : (unsigned short)0;
}

// ---------------- per-(quarter-chunk), per-range edge counts ----------------
__global__ __launch_bounds__(1024) void k_cnt8(const int* __restrict__ col,
                                               int* __restrict__ bcnt, int E, int CE) {
  __shared__ int scnt[16][8];
  int bid = blockIdx.x;
  int c = bid >> 2, q = bid & 3;
  int e0 = c * CE, e1 = min(E, e0 + CE);
  int S = (CE + 3) >> 2;
  int s0 = e0 + q * S, s1 = min(e1, s0 + S);
  int t = threadIdx.x, wv = t >> 6, lane = t & 63;
  int cr[8] = {0, 0, 0, 0, 0, 0, 0, 0};
  for (int e = s0 + t; e < s1; e += 1024) {
    int r = col[e] / BPR;
#pragma unroll
    for (int rr = 0; rr < 8; rr++) cr[rr] += (r == rr) ? 1 : 0;
  }
#pragma unroll
  for (int rr = 0; rr < 8; rr++) {
    int v = cr[rr];
#pragma unroll
    for (int d = 32; d > 0; d >>= 1) v += __shfl_down(v, d);
    if (lane == 0) scnt[wv][rr] = v;
  }
  __syncthreads();
  if (t < 8) {
    int s = 0;
    for (int i = 0; i < 16; i++) s += scnt[i][t];
    bcnt[(c * 8 + t) * 4 + q] = s;
  }
}

// ---------------- exclusive scan of 2048 bucket counts -> boff ----------------
__global__ void k_scan8(const int* __restrict__ bcnt, int* __restrict__ boff) {
  __shared__ int s[1024];
  int t = threadIdx.x;
  int v0 = bcnt[2 * t], v1 = bcnt[2 * t + 1];
  int pv = v0 + v1;
  s[t] = pv;
  __syncthreads();
  for (int d = 1; d < 1024; d <<= 1) {
    int x = (t >= d) ? s[t - d] : 0;
    __syncthreads();
    s[t] += x;
    __syncthreads();
  }
  int ex = s[t] - pv;
  boff[2 * t] = ex;
  boff[2 * t + 1] = ex + v0;
  if (t == 1023) boff[2048] = s[1023];
}

// ---------------- scatter edges into private buckets; LDS cursors ----------------
__global__ __launch_bounds__(1024) void k_scatter(const int* __restrict__ col,
                                                  const int* __restrict__ row,
                                                  const float* __restrict__ w,
                                                  const int* __restrict__ boff,
                                                  unsigned short* __restrict__ bloc,
                                                  uint2* __restrict__ brw, int E, int CE) {
  __shared__ int cur[8];
  int bid = blockIdx.x;
  int c = bid >> 2, q = bid & 3;
  int t = threadIdx.x;
  if (t < 8) cur[t] = boff[(c * 8 + t) * 4 + q];
  __syncthreads();
  int e0 = c * CE, e1 = min(E, e0 + CE);
  int S = (CE + 3) >> 2;
  int s0 = e0 + q * S, s1 = min(e1, s0 + S);
  for (int e = s0 + t; e < s1; e += 1024) {
    int b = col[e];
    int r = b / BPR;
    int pos = atomicAdd(&cur[r], 1);
    bloc[pos] = (unsigned short)(b - r * BPR);
    brw[pos] = make_uint2((unsigned)row[e], __float_as_uint(w[e]));
  }
}

// ---------------- histogram from bucket locals ----------------
__global__ __launch_bounds__(1024) void k_hist2(const unsigned short* __restrict__ bloc,
                                                const int* __restrict__ boff,
                                                unsigned* __restrict__ partial, int ranges) {
  __shared__ unsigned lds[WPR];
  int r = blockIdx.x % ranges;
  int c = blockIdx.x / ranges;
  int t = threadIdx.x;
  for (int i = t; i < WPR; i += 1024) lds[i] = 0;
  __syncthreads();
  int s0 = boff[(c * 8 + r) * 4], s1 = boff[(c * 8 + r) * 4 + 4];
  for (int i = s0 + t; i < s1; i += 1024) {
    int local = bloc[i];
    atomicAdd(&lds[local >> 1], 1u << (16 * (local & 1)));
  }
  __syncthreads();
  unsigned* dst = partial + ((size_t)r * CHUNKS + c) * WPR;
  for (int i = t; i < WPR; i += 1024) dst[i] = lds[i];
}

// ---------------- per-bin prefix over chunks ----------------
__global__ void k_colprefix(const unsigned* __restrict__ partial,
                            unsigned short* __restrict__ rel,
                            int* __restrict__ cnt, int N, int npad) {
  int bin = blockIdx.x * blockDim.x + threadIdx.x;
  if (bin >= N) return;
  int r = bin / BPR, local = bin % BPR;
  int word = local >> 1, sh = 16 * (local & 1);
  const unsigned* p = partial + (size_t)r * CHUNKS * WPR + word;
  unsigned acc = 0;
  for (int c = 0; c < CHUNKS; c++) {
    unsigned v = (p[(size_t)c * WPR] >> sh) & 0xFFFFu;
    rel[(size_t)c * npad + bin] = (unsigned short)acc;
    acc += v;
  }
  cnt[bin] = (int)acc;
}

// ---------------- exclusive scan of cnt -> offs ----------------
__global__ void k_scan1(const int* __restrict__ cnt, int* __restrict__ offs,
                        int* __restrict__ bsum, int n) {
  __shared__ int s[1024];
  int tid = threadIdx.x;
  int i = blockIdx.x * 1024 + tid;
  int v = (i < n) ? cnt[i] : 0;
  s[tid] = v;
  __syncthreads();
  for (int d = 1; d < 1024; d <<= 1) {
    int t = (tid >= d) ? s[tid - d] : 0;
    __syncthreads();
    s[tid] += t;
    __syncthreads();
  }
  if (i < n) offs[i] = s[tid] - v;
  if (tid == 1023) bsum[blockIdx.x] = s[1023];
}

__global__ void k_scan2(int* __restrict__ bsum, int nb) {
  __shared__ int s[256];
  __shared__ int carry;
  int t = threadIdx.x;
  if (t == 0) carry = 0;
  __syncthreads();
  for (int base = 0; base < nb; base += 256) {
    int v = (base + t < nb) ? bsum[base + t] : 0;
    s[t] = v;
    __syncthreads();
    for (int d = 1; d < 256; d <<= 1) {
      int x = (t >= d) ? s[t - d] : 0;
      __syncthreads();
      s[t] += x;
      __syncthreads();
    }
    int total = s[255];
    if (base + t < nb) bsum[base + t] = carry + s[t] - v;
    __syncthreads();
    if (t == 0) carry += total;
    __syncthreads();
  }
}

__global__ void k_scan3(int* __restrict__ offs, const int* __restrict__ bsum,
                        int n, int total) {
  int i = blockIdx.x * 1024 + threadIdx.x;
  if (i < n) offs[i] += bsum[blockIdx.x];
  if (i == 0) offs[n] = total;
}

// ------- CSR fill from buckets; PACK dest-local into csr8.x upper bits (src|local<<17) ------
__global__ __launch_bounds__(1024) void k_fill2(const unsigned short* __restrict__ bloc,
                                                const uint2* __restrict__ brw,
                                                const int* __restrict__ boff,
                                                const int* __restrict__ offs,
                                                const unsigned short* __restrict__ rel,
                                                uint2* __restrict__ csr8,
                                                int N, int npad, int ranges) {
  __shared__ unsigned cur[WPR];
  int r = blockIdx.x % ranges;
  int c = blockIdx.x / ranges;
  int lo = r * BPR;
  int hi = min(N, lo + BPR);
  int t = threadIdx.x;
  const unsigned* rsrc = (const unsigned*)(rel + (size_t)c * npad + lo);
  int nw = (hi - lo + 1) >> 1;
  for (int i = t; i < nw; i += 1024) cur[i] = rsrc[i];
  __syncthreads();
  int s0 = boff[(c * 8 + r) * 4], s1 = boff[(c * 8 + r) * 4 + 4];
  for (int i = s0 + t; i < s1; i += 1024) {
    int local = bloc[i];
    int sh = 16 * (local & 1);
    unsigned old = atomicAdd(&cur[local >> 1], 1u << sh);
    unsigned myrel = (old >> sh) & 0xFFFFu;
    int pos = offs[lo + local] + (int)myrel;
    uint2 b = brw[i];
    csr8[pos] = make_uint2(b.x | ((unsigned)local << 17), b.y);
  }
}

// ---------------- weighted degree -> dinv, wave per node ----------------
__global__ void k_deg2(const uint2* __restrict__ csr8, const int* __restrict__ offs,
                       float* __restrict__ dinv, int n) {
  int wid = (blockIdx.x * blockDim.x + threadIdx.x) >> 6;
  int lane = threadIdx.x & 63;
  if (wid >= n) return;
  int s = offs[wid], e = offs[wid + 1];
  float acc = 0.f;
  for (int k = s + lane; k < e; k += 64) acc += __uint_as_float(csr8[k].y);
#pragma unroll
  for (int d = 32; d > 0; d >>= 1) acc += __shfl_down(acc, d);
  if (lane == 0) dinv[wid] = rsqrtf(1.0f + acc);   // +1 = self loop weight
}

// ---------------- in-place norm: csr8.y <- dinv[src] * w (src = low 17 bits) ----------------
__global__ void k_norm(uint2* __restrict__ csr8, const float* __restrict__ dinv, int E) {
  int i = blockIdx.x * blockDim.x + threadIdx.x;
  if (i >= E) return;
  uint2 v = csr8[i];
  csr8[i].y = __float_as_uint(dinv[v.x & 0x1FFFFu] * __uint_as_float(v.y));
}

// ------- edge-parallel layer-1: segmented-reduce into LDS + fused W1 MLP + BN partials -----
// Block = 64 dest nodes. 16 contiguous edge sub-spans (one per 16-lane group), run-detected.
__global__ __launch_bounds__(256) void k_agg1e(const unsigned short* __restrict__ x16b,
                                               const int* __restrict__ offs,
                                               const uint2* __restrict__ csr8,
                                               const float* __restrict__ dinv,
                                               const float* __restrict__ W1,
                                               const float* __restrict__ b1,
                                               unsigned short* __restrict__ h,
                                               float2* __restrict__ pbn, int N) {
  __shared__ float Ws[F0 * F1];
  __shared__ float bs[F1];
  __shared__ float sacc[NN1 * 16];
  __shared__ unsigned short sx[NN1 * 16];
  __shared__ float sdinv[NN1];
  __shared__ float sS[4][64], sQ[4][64];
  int t = threadIdx.x;
  int bid = blockIdx.x;
  int n0 = bid * NN1;
  int nn = min(NN1, N - n0);
  int lbase = n0 - (n0 / BPR) * BPR;
  for (int i = t; i < F0 * F1; i += 256) Ws[i] = W1[i];
  if (t < F1) bs[t] = b1[t];
  ((uint2*)sx)[t] = ((const uint2*)(x16b + (size_t)n0 * 16))[t];  // may over-read tail: benign
  if (t < NN1) sdinv[t] = (t < nn) ? dinv[n0 + t] : 0.f;
  for (int i = t; i < NN1 * 16; i += 256) sacc[i] = 0.f;
  __syncthreads();
  int ebase = offs[n0], eend = offs[n0 + nn];
  int slot = t >> 4, f = t & 15;
  int nsub = (eend - ebase + 15) >> 4;
  int gs = ebase + slot * nsub;
  int ge = min(eend, gs + nsub);
  float sum = 0.f;
  int cid = -1;
  int e = gs;
  for (; e + 4 <= ge; e += 4) {
    uint2 v0 = csr8[e], v1 = csr8[e + 1], v2 = csr8[e + 2], v3 = csr8[e + 3];
    int i0 = (int)(v0.x >> 17) - lbase, i1 = (int)(v1.x >> 17) - lbase;
    int i2 = (int)(v2.x >> 17) - lbase, i3 = (int)(v3.x >> 17) - lbase;
    float c0 = __uint_as_float(v0.y) * bf2f(x16b[(size_t)(v0.x & 0x1FFFFu) * 16 + f]);
    float c1 = __uint_as_float(v1.y) * bf2f(x16b[(size_t)(v1.x & 0x1FFFFu) * 16 + f]);
    float c2 = __uint_as_float(v2.y) * bf2f(x16b[(size_t)(v2.x & 0x1FFFFu) * 16 + f]);
    float c3 = __uint_as_float(v3.y) * bf2f(x16b[(size_t)(v3.x & 0x1FFFFu) * 16 + f]);
    bool sm;
    sm = (i0 == cid); if (!sm && cid >= 0) atomicAdd(&sacc[cid * 16 + f], sum);
    sum = sm ? sum + c0 : c0; cid = i0;
    sm = (i1 == cid); if (!sm) atomicAdd(&sacc[cid * 16 + f], sum);
    sum = sm ? sum + c1 : c1; cid = i1;
    sm = (i2 == cid); if (!sm) atomicAdd(&sacc[cid * 16 + f], sum);
    sum = sm ? sum + c2 : c2; cid = i2;
    sm = (i3 == cid); if (!sm) atomicAdd(&sacc[cid * 16 + f], sum);
    sum = sm ? sum + c3 : c3; cid = i3;
  }
  for (; e < ge; e++) {
    uint2 v0 = csr8[e];
    int i0 = (int)(v0.x >> 17) - lbase;
    float c0 = __uint_as_float(v0.y) * bf2f(x16b[(size_t)(v0.x & 0x1FFFFu) * 16 + f]);
    bool sm = (i0 == cid);
    if (!sm && cid >= 0) atomicAdd(&sacc[cid * 16 + f], sum);
    sum = sm ? sum + c0 : c0; cid = i0;
  }
  if (cid >= 0) atomicAdd(&sacc[cid * 16 + f], sum);
  __syncthreads();
  // transform: a[nd][k] = di*(acc + di*x_self)
  for (int i = t; i < NN1 * 16; i += 256) {
    float di = sdinv[i >> 4];
    sacc[i] = di * (sacc[i] + di * bf2f(sx[i]));
  }
  __syncthreads();
  // MLP + BN partials: thread (wv, ff) handles nodes wv+4i, feature ff
  int ff = t & 63, wv = t >> 6;
  float S = 0.f, Q = 0.f;
  for (int i = 0; i < 16; i++) {
    int nd = wv + 4 * i;
    if (nd < nn) {
      float o = bs[ff];
#pragma unroll
      for (int k = 0; k < F0; k++) o += sacc[nd * 16 + k] * Ws[k * F1 + ff];
      h[(size_t)(n0 + nd) * F1 + ff] = f2bf(o);
      S += o; Q += o * o;
    }
  }
  sS[wv][ff] = S; sQ[wv][ff] = Q;
  __syncthreads();
  if (t < 64)
    pbn[(size_t)bid * 64 + t] =
        make_float2(sS[0][t] + sS[1][t] + sS[2][t] + sS[3][t],
                    sQ[0][t] + sQ[1][t] + sQ[2][t] + sQ[3][t]);
}

// mid-level BN reduction over nrows partial rows
__global__ void k_bn_mid(const float2* __restrict__ pbn, float2* __restrict__ pbn2, int nrows) {
  __shared__ float sS[4][64], sQ[4][64];
  int t = threadIdx.x;
  int f = t & 63, g = t >> 6;
  int rpb = (nrows + 63) / 64;
  int b0 = blockIdx.x * rpb;
  int bend = min(nrows, b0 + rpb);
  float S = 0.f, Q = 0.f;
  for (int b = b0 + g; b < bend; b += 4) {
    float2 v = pbn[(size_t)b * 64 + f];
    S += v.x; Q += v.y;
  }
  sS[g][f] = S; sQ[g][f] = Q;
  __syncthreads();
  if (t < 64)
    pbn2[(size_t)blockIdx.x * 64 + t] =
        make_float2(sS[0][t] + sS[1][t] + sS[2][t] + sS[3][t],
                    sQ[0][t] + sQ[1][t] + sQ[2][t] + sQ[3][t]);
}

__global__ void k_bn_final(const float2* __restrict__ pbn2, const float* __restrict__ gamma,
                           const float* __restrict__ beta, float* __restrict__ scalef,
                           float* __restrict__ shiftf, int n) {
  __shared__ double sS[4][64], sQ[4][64];
  int t = threadIdx.x;
  int f = t & 63, g = t >> 6;
  double S = 0.0, Q = 0.0;
  for (int b = g; b < 64; b += 4) {
    float2 v = pbn2[(size_t)b * 64 + f];
    S += v.x; Q += v.y;
  }
  sS[g][f] = S; sQ[g][f] = Q;
  __syncthreads();
  if (t < 64) {
    double SS = sS[0][t] + sS[1][t] + sS[2][t] + sS[3][t];
    double QQ = sQ[0][t] + sQ[1][t] + sQ[2][t] + sQ[3][t];
    double mean = SS / (double)n;
    double var = QQ / (double)n - mean * mean;
    if (var < 0.0) var = 0.0;
    float scale = gamma[t] * (float)(1.0 / sqrt(var + 1e-5));
    scalef[t] = scale;
    shiftf[t] = beta[t] - (float)mean * scale;
  }
}

// ---------------- hn = bf16(relu(bn(h))) elementwise ----------------
__global__ void k_hn(const unsigned short* __restrict__ h, const float* __restrict__ scalef,
                     const float* __restrict__ shiftf, unsigned short* __restrict__ hn,
                     int total4) {
  __shared__ float ssc[64], ssf[64];
  int t = threadIdx.x;
  if (t < 64) { ssc[t] = scalef[t]; ssf[t] = shiftf[t]; }
  __syncthreads();
  int idx = blockIdx.x * blockDim.x + t;
  int stride = gridDim.x * blockDim.x;
  const unsigned long long* hp = (const unsigned long long*)h;
  unsigned long long* hnp = (unsigned long long*)hn;
  for (int i = idx; i < total4; i += stride) {
    unsigned long long vv = hp[i];
    int f0 = (i * 4) & 63;
    float a = fmaxf(fmaf(bf2f_lo((unsigned)vv), ssc[f0 + 0], ssf[f0 + 0]), 0.f);
    float b = fmaxf(fmaf(bf2f_hi((unsigned)vv), ssc[f0 + 1], ssf[f0 + 1]), 0.f);
    float c = fmaxf(fmaf(bf2f_lo((unsigned)(vv >> 32)), ssc[f0 + 2], ssf[f0 + 2]), 0.f);
    float d = fmaxf(fmaf(bf2f_hi((unsigned)(vv >> 32)), ssc[f0 + 3], ssf[f0 + 3]), 0.f);
    hnp[i] = (unsigned long long)f2bf(a) | ((unsigned long long)f2bf(b) << 16) |
             ((unsigned long long)f2bf(c) << 32) | ((unsigned long long)f2bf(d) << 48);
  }
}

// ------- edge-parallel layer-2: segmented-reduce hn gathers into LDS [64][64] -------
__global__ __launch_bounds__(256) void k_agg2e(const unsigned short* __restrict__ hn,
                                               const int* __restrict__ offs,
                                               const uint2* __restrict__ csr8,
                                               const float* __restrict__ dinv,
                                               float* __restrict__ agg2, int N) {
  __shared__ float sacc[NN1 * F1];   // 16 KiB
  __shared__ float sdinv[NN1];
  int t = threadIdx.x;
  int bid = blockIdx.x;
  int n0 = bid * NN1;
  int nn = min(NN1, N - n0);
  int lbase = n0 - (n0 / BPR) * BPR;
  int lane = t & 63, wv = t >> 6;
  if (t < NN1) sdinv[t] = (t < nn) ? dinv[n0 + t] : 0.f;
  for (int i = t; i < NN1 * F1; i += 256) sacc[i] = 0.f;
  __syncthreads();
  int ebase = offs[n0], eend = offs[n0 + nn];
  int nsub = (eend - ebase + 3) >> 2;
  int gs = ebase + wv * nsub;
  int ge = min(eend, gs + nsub);
  float sum = 0.f;
  int cid = -1;
  int e = gs;
  for (; e + 8 <= ge; e += 8) {
    uint2 v[8];
#pragma unroll
    for (int j = 0; j < 8; j++) v[j] = csr8[e + j];
    float c[8];
    int idx[8];
#pragma unroll
    for (int j = 0; j < 8; j++) {
      idx[j] = (int)(v[j].x >> 17) - lbase;
      c[j] = __uint_as_float(v[j].y) *
             bf2f(hn[(size_t)(v[j].x & 0x1FFFFu) * F1 + lane]);
    }
#pragma unroll
    for (int j = 0; j < 8; j++) {
      bool sm = (idx[j] == cid);
      if (!sm && cid >= 0) atomicAdd(&sacc[cid * F1 + lane], sum);
      sum = sm ? sum + c[j] : c[j];
      cid = idx[j];
    }
  }
  for (; e < ge; e++) {
    uint2 v0 = csr8[e];
    int i0 = (int)(v0.x >> 17) - lbase;
    float c0 = __uint_as_float(v0.y) * bf2f(hn[(size_t)(v0.x & 0x1FFFFu) * F1 + lane]);
    bool sm = (i0 == cid);
    if (!sm && cid >= 0) atomicAdd(&sacc[cid * F1 + lane], sum);
    sum = sm ? sum + c0 : c0;
    cid = i0;
  }
  if (cid >= 0) atomicAdd(&sacc[cid * F1 + lane], sum);
  __syncthreads();
  for (int i = 0; i < 16; i++) {
    int nd = wv + 4 * i;
    if (nd < nn) {
      float di = sdinv[nd];
      float self = bf2f(hn[(size_t)(n0 + nd) * F1 + lane]);
      agg2[(size_t)(n0 + nd) * F1 + lane] = di * (sacc[nd * F1 + lane] + di * self);
    }
  }
}

// ---------------- out = agg2 @ W2 + b2, register-tiled GEMM ----------------
__global__ __launch_bounds__(256) void k_gemm2(const float* __restrict__ agg2,
                                               const float* __restrict__ W2,
                                               const float* __restrict__ b2,
                                               float* __restrict__ out, int n) {
  __shared__ float Ws[F1 * F2];
  __shared__ float As[F1][TN2];
  int t = threadIdx.x;
  for (int i = t; i < F1 * F2 / 4; i += 256) ((float4*)Ws)[i] = ((const float4*)W2)[i];
  int nb = blockIdx.x * TN2;
  int node = t & 127;
  int kh = (t >> 7) * 32;
  int gnode = nb + node;
  if (gnode < n) {
    const float4* src = (const float4*)(agg2 + (size_t)gnode * F1 + kh);
#pragma unroll
    for (int j = 0; j < 8; j++) {
      float4 v = src[j];
      As[kh + j * 4 + 0][node] = v.x;
      As[kh + j * 4 + 1][node] = v.y;
      As[kh + j * 4 + 2][node] = v.z;
      As[kh + j * 4 + 3][node] = v.w;
    }
  } else {
#pragma unroll
    for (int j = 0; j < 8; j++) {
      As[kh + j * 4 + 0][node] = 0.f;
      As[kh + j * 4 + 1][node] = 0.f;
      As[kh + j * 4 + 2][node] = 0.f;
      As[kh + j * 4 + 3][node] = 0.f;
    }
  }
  __syncthreads();

  int f0 = (t & 15) * 8;
  int n0 = (t >> 4) * 8;
  float acc[8][8];
  float bv[8];
#pragma unroll
  for (int j = 0; j < 8; j++) bv[j] = b2[f0 + j];
#pragma unroll
  for (int i = 0; i < 8; i++)
#pragma unroll
    for (int j = 0; j < 8; j++) acc[i][j] = bv[j];

#pragma unroll 4
  for (int k = 0; k < F1; k++) {
    float4 a0 = *(const float4*)&As[k][n0];
    float4 a1 = *(const float4*)&As[k][n0 + 4];
    float4 w0 = *(const float4*)&Ws[k * F2 + f0];
    float4 w1 = *(const float4*)&Ws[k * F2 + f0 + 4];
    float a[8] = {a0.x, a0.y, a0.z, a0.w, a1.x, a1.y, a1.z, a1.w};
    float w[8] = {w0.x, w0.y, w0.z, w0.w, w1.x, w1.y, w1.z, w1.w};
#pragma unroll
    for (int i = 0; i < 8; i++)
#pragma unroll
      for (int j = 0; j < 8; j++) acc[i][j] += a[i] * w[j];
  }

#pragma unroll
  for (int i = 0; i < 8; i++) {
    int gi = nb + n0 + i;
    if (gi < n) {
      float4 o0 = {acc[i][0], acc[i][1], acc[i][2], acc[i][3]};
      float4 o1 = {acc[i][4], acc[i][5], acc[i][6], acc[i][7]};
      *(float4*)&out[(size_t)gi * F2 + f0] = o0;
      *(float4*)&out[(size_t)gi * F2 + f0 + 4] = o1;
    }
  }
}

extern "C" void kernel_launch(void* const* d_in, const int* in_sizes, int n_in,
                              void* d_out, int out_size, void* d_ws, size_t ws_size,
                              hipStream_t stream) {
  const float* x     = (const float*)d_in[0];
  const int*   ei    = (const int*)d_in[1];
  const float* ew    = (const float*)d_in[2];
  const float* W1    = (const float*)d_in[3];
  const float* b1    = (const float*)d_in[4];
  const float* gamma = (const float*)d_in[5];
  const float* beta  = (const float*)d_in[6];
  const float* W2    = (const float*)d_in[7];
  const float* b2    = (const float*)d_in[8];
  float* out = (float*)d_out;

  int N = in_sizes[0] / F0;
  int E = in_sizes[1] / 2;
  const int* row = ei;
  const int* col = ei + E;
  if (N <= 0) return;

  int CE = (E + CHUNKS - 1) / CHUNKS;
  int RANGES = (N + BPR - 1) / BPR;
  int npad = RANGES * BPR;
  int NBLK = (N + NN1 - 1) / NN1;

  // ---- workspace carve-up (with overlays) ----
  char* p = (char*)d_ws;
  auto alloc = [&](size_t bytes) -> void* {
    void* r = (void*)p;
    p += (bytes + 255) & ~(size_t)255;
    return r;
  };
  size_t partial_bytes = ((size_t)RANGES * CHUNKS * WPR * 4 + 255) & ~(size_t)255;
  size_t rel_bytes     = (size_t)CHUNKS * npad * 2;
  size_t h_bytes       = (size_t)N * F1 * 2;
  size_t region_bytes  = partial_bytes + rel_bytes;
  if (h_bytes > region_bytes) region_bytes = h_bytes;

  float*          dinv    = (float*)alloc((size_t)N * 4);
  int*            cnt     = (int*)alloc((size_t)N * 4);
  int*            offs    = (int*)alloc((size_t)(N + 1) * 4);
  int             NB      = (N + 1023) / 1024;
  int*            bsum    = (int*)alloc((size_t)NB * 4);
  uint2*          csr8    = (uint2*)alloc((size_t)E * 8);
  char*           region  = (char*)alloc(region_bytes);
  unsigned*       partial = (unsigned*)region;
  unsigned short* rel     = (unsigned short*)(region + partial_bytes);
  unsigned short* h       = (unsigned short*)region;     // after fill2
  unsigned short* x16b    = (unsigned short*)alloc((size_t)N * 16 * 2);
  unsigned short* hn      = (unsigned short*)alloc((size_t)N * F1 * 2);
  float*          agg2    = (float*)alloc((size_t)N * F1 * 4);   // hosts buckets pre-fill
  float2*         pbn     = (float2*)alloc((size_t)NBLK * 64 * 8);
  float2*         pbn2    = (float2*)alloc((size_t)64 * 64 * 8);
  float*          scalef  = (float*)alloc(64 * 4);
  float*          shiftf  = (float*)alloc(64 * 4);
  int*            bcnt    = (int*)alloc((size_t)NBKT * 4);
  int*            boff    = (int*)alloc((size_t)(NBKT + 1) * 4);
  size_t bloc_bytes = (((size_t)E * 2) + 255) & ~(size_t)255;
  unsigned short* bloc = (unsigned short*)agg2;
  uint2*          brw  = (uint2*)((char*)agg2 + bloc_bytes);
  (void)ws_size; (void)n_in; (void)out_size;

  int bW  = (N + 3) / 4;
  int bG2 = (N + TN2 - 1) / TN2;
  int gRC = CHUNKS * RANGES;

  k_pad<<<(N * 16 + 255) / 256, 256, 0, stream>>>(x, x16b, N);
  k_cnt8<<<CHUNKS * 4, 1024, 0, stream>>>(col, bcnt, E, CE);
  k_scan8<<<1, 1024, 0, stream>>>(bcnt, boff);
  k_scatter<<<CHUNKS * 4, 1024, 0, stream>>>(col, row, ew, boff, bloc, brw, E, CE);
  k_hist2<<<gRC, 1024, 0, stream>>>(bloc, boff, partial, RANGES);
  k_colprefix<<<(N + 255) / 256, 256, 0, stream>>>(partial, rel, cnt, N, npad);
  k_scan1<<<NB, 1024, 0, stream>>>(cnt, offs, bsum, N);
  k_scan2<<<1, 256, 0, stream>>>(bsum, NB);
  k_scan3<<<NB, 1024, 0, stream>>>(offs, bsum, N, E);
  k_fill2<<<gRC, 1024, 0, stream>>>(bloc, brw, boff, offs, rel, csr8, N, npad, RANGES);
  k_deg2<<<bW, 256, 0, stream>>>(csr8, offs, dinv, N);
  k_norm<<<(E + 255) / 256, 256, 0, stream>>>(csr8, dinv, E);
  k_agg1e<<<NBLK, 256, 0, stream>>>(x16b, offs, csr8, dinv, W1, b1, h, pbn, N);
  k_bn_mid<<<64, 256, 0, stream>>>(pbn, pbn2, NBLK);
  k_bn_final<<<1, 256, 0, stream>>>(pbn2, gamma, beta, scalef, shiftf, N);
  k_hn<<<2048, 256, 0, stream>>>(h, scalef, shiftf, hn, N * F1 / 4);
  k_agg2e<<<NBLK, 256, 0, stream>>>(hn, offs, csr8, dinv, agg2, N);
  k_gemm2<<<bG2, 256, 0, stream>>>(agg2, W2, b2, out, N);
}

// Round 13
// 214.099 us; speedup vs baseline: 1.1497x; 1.1497x over previous
//
#include <hip/hip_runtime.h>

#define F0 11
#define F1 64
#define F2 128
#define TN2 128      // nodes per block in k_gemm2

#define CHUNKS 64
#define BPR 12544    // bins per range; 12544%64==0; supports N <= 8*BPR = 100352 (src fits 17 bits)
#define WPR (BPR / 2)
#define NBKT (CHUNKS * 8 * 4)
#define NN1 64       // nodes per block in edge-parallel agg1

// bf16 helpers (round-to-nearest-even)
__device__ __forceinline__ unsigned short f2bf(float v) {
  unsigned u = __float_as_uint(v);
  unsigned r = u + 0x7FFFu + ((u >> 16) & 1u);
  return (unsigned short)(r >> 16);
}
__device__ __forceinline__ float bf2f(unsigned short s) {
  return __uint_as_float(((unsigned)s) << 16);
}
__device__ __forceinline__ float bf2f_lo(unsigned v) { return __uint_as_float(v << 16); }
__device__ __forceinline__ float bf2f_hi(unsigned v) { return __uint_as_float(v & 0xFFFF0000u); }

// ---------------- pad x (11 fp32) -> x16b (16 bf16 per row) ----------------
__global__ void k_pad(const float* __restrict__ x, unsigned short* __restrict__ x16b, int n) {
  int i = blockIdx.x * blockDim.x + threadIdx.x;
  if (i >= n * 16) return;
  int r = i >> 4, f = i & 15;
  x16b[i] = (f < F0) ? f2bf(x[(size_t)r * F0 + f]) : (unsigned short)0;
}

// ---------------- per-(quarter-chunk), per-range edge counts ----------------
__global__ __launch_bounds__(1024) void k_cnt8(const int* __restrict__ col,
                                               int* __restrict__ bcnt, int E, int CE) {
  __shared__ int scnt[16][8];
  int bid = blockIdx.x;
  int c = bid >> 2, q = bid & 3;
  int e0 = c * CE, e1 = min(E, e0 + CE);
  int S = (CE + 3) >> 2;
  int s0 = e0 + q * S, s1 = min(e1, s0 + S);
  int t = threadIdx.x, wv = t >> 6, lane = t & 63;
  int cr[8] = {0, 0, 0, 0, 0, 0, 0, 0};
  for (int e = s0 + t; e < s1; e += 1024) {
    int r = col[e] / BPR;
#pragma unroll
    for (int rr = 0; rr < 8; rr++) cr[rr] += (r == rr) ? 1 : 0;
  }
#pragma unroll
  for (int rr = 0; rr < 8; rr++) {
    int v = cr[rr];
#pragma unroll
    for (int d = 32; d > 0; d >>= 1) v += __shfl_down(v, d);
    if (lane == 0) scnt[wv][rr] = v;
  }
  __syncthreads();
  if (t < 8) {
    int s = 0;
    for (int i = 0; i < 16; i++) s += scnt[i][t];
    bcnt[(c * 8 + t) * 4 + q] = s;
  }
}

// ---------------- exclusive scan of 2048 bucket counts -> boff ----------------
__global__ void k_scan8(const int* __restrict__ bcnt, int* __restrict__ boff) {
  __shared__ int s[1024];
  int t = threadIdx.x;
  int v0 = bcnt[2 * t], v1 = bcnt[2 * t + 1];
  int pv = v0 + v1;
  s[t] = pv;
  __syncthreads();
  for (int d = 1; d < 1024; d <<= 1) {
    int x = (t >= d) ? s[t - d] : 0;
    __syncthreads();
    s[t] += x;
    __syncthreads();
  }
  int ex = s[t] - pv;
  boff[2 * t] = ex;
  boff[2 * t + 1] = ex + v0;
  if (t == 1023) boff[2048] = s[1023];
}

// ---------------- scatter edges into private buckets; LDS cursors ----------------
__global__ __launch_bounds__(1024) void k_scatter(const int* __restrict__ col,
                                                  const int* __restrict__ row,
                                                  const float* __restrict__ w,
                                                  const int* __restrict__ boff,
                                                  unsigned short* __restrict__ bloc,
                                                  uint2* __restrict__ brw, int E, int CE) {
  __shared__ int cur[8];
  int bid = blockIdx.x;
  int c = bid >> 2, q = bid & 3;
  int t = threadIdx.x;
  if (t < 8) cur[t] = boff[(c * 8 + t) * 4 + q];
  __syncthreads();
  int e0 = c * CE, e1 = min(E, e0 + CE);
  int S = (CE + 3) >> 2;
  int s0 = e0 + q * S, s1 = min(e1, s0 + S);
  for (int e = s0 + t; e < s1; e += 1024) {
    int b = col[e];
    int r = b / BPR;
    int pos = atomicAdd(&cur[r], 1);
    bloc[pos] = (unsigned short)(b - r * BPR);
    brw[pos] = make_uint2((unsigned)row[e], __float_as_uint(w[e]));
  }
}

// ---------------- histogram from bucket locals ----------------
__global__ __launch_bounds__(1024) void k_hist2(const unsigned short* __restrict__ bloc,
                                                const int* __restrict__ boff,
                                                unsigned* __restrict__ partial, int ranges) {
  __shared__ unsigned lds[WPR];
  int r = blockIdx.x % ranges;
  int c = blockIdx.x / ranges;
  int t = threadIdx.x;
  for (int i = t; i < WPR; i += 1024) lds[i] = 0;
  __syncthreads();
  int s0 = boff[(c * 8 + r) * 4], s1 = boff[(c * 8 + r) * 4 + 4];
  for (int i = s0 + t; i < s1; i += 1024) {
    int local = bloc[i];
    atomicAdd(&lds[local >> 1], 1u << (16 * (local & 1)));
  }
  __syncthreads();
  unsigned* dst = partial + ((size_t)r * CHUNKS + c) * WPR;
  for (int i = t; i < WPR; i += 1024) dst[i] = lds[i];
}

// ---------------- per-bin prefix over chunks ----------------
__global__ void k_colprefix(const unsigned* __restrict__ partial,
                            unsigned short* __restrict__ rel,
                            int* __restrict__ cnt, int N, int npad) {
  int bin = blockIdx.x * blockDim.x + threadIdx.x;
  if (bin >= N) return;
  int r = bin / BPR, local = bin % BPR;
  int word = local >> 1, sh = 16 * (local & 1);
  const unsigned* p = partial + (size_t)r * CHUNKS * WPR + word;
  unsigned acc = 0;
  for (int c = 0; c < CHUNKS; c++) {
    unsigned v = (p[(size_t)c * WPR] >> sh) & 0xFFFFu;
    rel[(size_t)c * npad + bin] = (unsigned short)acc;
    acc += v;
  }
  cnt[bin] = (int)acc;
}

// ---------------- exclusive scan of cnt -> offs ----------------
__global__ void k_scan1(const int* __restrict__ cnt, int* __restrict__ offs,
                        int* __restrict__ bsum, int n) {
  __shared__ int s[1024];
  int tid = threadIdx.x;
  int i = blockIdx.x * 1024 + tid;
  int v = (i < n) ? cnt[i] : 0;
  s[tid] = v;
  __syncthreads();
  for (int d = 1; d < 1024; d <<= 1) {
    int t = (tid >= d) ? s[tid - d] : 0;
    __syncthreads();
    s[tid] += t;
    __syncthreads();
  }
  if (i < n) offs[i] = s[tid] - v;
  if (tid == 1023) bsum[blockIdx.x] = s[1023];
}

__global__ void k_scan2(int* __restrict__ bsum, int nb) {
  __shared__ int s[256];
  __shared__ int carry;
  int t = threadIdx.x;
  if (t == 0) carry = 0;
  __syncthreads();
  for (int base = 0; base < nb; base += 256) {
    int v = (base + t < nb) ? bsum[base + t] : 0;
    s[t] = v;
    __syncthreads();
    for (int d = 1; d < 256; d <<= 1) {
      int x = (t >= d) ? s[t - d] : 0;
      __syncthreads();
      s[t] += x;
      __syncthreads();
    }
    int total = s[255];
    if (base + t < nb) bsum[base + t] = carry + s[t] - v;
    __syncthreads();
    if (t == 0) carry += total;
    __syncthreads();
  }
}

__global__ void k_scan3(int* __restrict__ offs, const int* __restrict__ bsum,
                        int n, int total) {
  int i = blockIdx.x * 1024 + threadIdx.x;
  if (i < n) offs[i] += bsum[blockIdx.x];
  if (i == 0) offs[n] = total;
}

// ------- CSR fill from buckets; PACK dest-local into csr8.x upper bits (src|local<<17) ------
__global__ __launch_bounds__(1024) void k_fill2(const unsigned short* __restrict__ bloc,
                                                const uint2* __restrict__ brw,
                                                const int* __restrict__ boff,
                                                const int* __restrict__ offs,
                                                const unsigned short* __restrict__ rel,
                                                uint2* __restrict__ csr8,
                                                int N, int npad, int ranges) {
  __shared__ unsigned cur[WPR];
  int r = blockIdx.x % ranges;
  int c = blockIdx.x / ranges;
  int lo = r * BPR;
  int hi = min(N, lo + BPR);
  int t = threadIdx.x;
  const unsigned* rsrc = (const unsigned*)(rel + (size_t)c * npad + lo);
  int nw = (hi - lo + 1) >> 1;
  for (int i = t; i < nw; i += 1024) cur[i] = rsrc[i];
  __syncthreads();
  int s0 = boff[(c * 8 + r) * 4], s1 = boff[(c * 8 + r) * 4 + 4];
  for (int i = s0 + t; i < s1; i += 1024) {
    int local = bloc[i];
    int sh = 16 * (local & 1);
    unsigned old = atomicAdd(&cur[local >> 1], 1u << sh);
    unsigned myrel = (old >> sh) & 0xFFFFu;
    int pos = offs[lo + local] + (int)myrel;
    uint2 b = brw[i];
    csr8[pos] = make_uint2(b.x | ((unsigned)local << 17), b.y);
  }
}

// ---------------- weighted degree -> dinv, wave per node ----------------
__global__ void k_deg2(const uint2* __restrict__ csr8, const int* __restrict__ offs,
                       float* __restrict__ dinv, int n) {
  int wid = (blockIdx.x * blockDim.x + threadIdx.x) >> 6;
  int lane = threadIdx.x & 63;
  if (wid >= n) return;
  int s = offs[wid], e = offs[wid + 1];
  float acc = 0.f;
  for (int k = s + lane; k < e; k += 64) acc += __uint_as_float(csr8[k].y);
#pragma unroll
  for (int d = 32; d > 0; d >>= 1) acc += __shfl_down(acc, d);
  if (lane == 0) dinv[wid] = rsqrtf(1.0f + acc);   // +1 = self loop weight
}

// ---------------- in-place norm: csr8.y <- dinv[src] * w (src = low 17 bits) ----------------
__global__ void k_norm(uint2* __restrict__ csr8, const float* __restrict__ dinv, int E) {
  int i = blockIdx.x * blockDim.x + threadIdx.x;
  if (i >= E) return;
  uint2 v = csr8[i];
  csr8[i].y = __float_as_uint(dinv[v.x & 0x1FFFFu] * __uint_as_float(v.y));
}

// ------- edge-parallel layer-1: segmented-reduce into LDS + fused W1 MLP + BN partials -----
__global__ __launch_bounds__(256) void k_agg1e(const unsigned short* __restrict__ x16b,
                                               const int* __restrict__ offs,
                                               const uint2* __restrict__ csr8,
                                               const float* __restrict__ dinv,
                                               const float* __restrict__ W1,
                                               const float* __restrict__ b1,
                                               unsigned short* __restrict__ h,
                                               float2* __restrict__ pbn, int N) {
  __shared__ float Ws[F0 * F1];
  __shared__ float bs[F1];
  __shared__ float sacc[NN1 * 16];
  __shared__ unsigned short sx[NN1 * 16];
  __shared__ float sdinv[NN1];
  __shared__ float sS[4][64], sQ[4][64];
  int t = threadIdx.x;
  int bid = blockIdx.x;
  int n0 = bid * NN1;
  int nn = min(NN1, N - n0);
  int lbase = n0 - (n0 / BPR) * BPR;
  for (int i = t; i < F0 * F1; i += 256) Ws[i] = W1[i];
  if (t < F1) bs[t] = b1[t];
  ((uint2*)sx)[t] = ((const uint2*)(x16b + (size_t)n0 * 16))[t];
  if (t < NN1) sdinv[t] = (t < nn) ? dinv[n0 + t] : 0.f;
  for (int i = t; i < NN1 * 16; i += 256) sacc[i] = 0.f;
  __syncthreads();
  int ebase = offs[n0], eend = offs[n0 + nn];
  int slot = t >> 4, f = t & 15;
  int nsub = (eend - ebase + 15) >> 4;
  int gs = ebase + slot * nsub;
  int ge = min(eend, gs + nsub);
  float sum = 0.f;
  int cid = -1;
  int e = gs;
  for (; e + 4 <= ge; e += 4) {
    uint2 v0 = csr8[e], v1 = csr8[e + 1], v2 = csr8[e + 2], v3 = csr8[e + 3];
    int i0 = (int)(v0.x >> 17) - lbase, i1 = (int)(v1.x >> 17) - lbase;
    int i2 = (int)(v2.x >> 17) - lbase, i3 = (int)(v3.x >> 17) - lbase;
    float c0 = __uint_as_float(v0.y) * bf2f(x16b[(size_t)(v0.x & 0x1FFFFu) * 16 + f]);
    float c1 = __uint_as_float(v1.y) * bf2f(x16b[(size_t)(v1.x & 0x1FFFFu) * 16 + f]);
    float c2 = __uint_as_float(v2.y) * bf2f(x16b[(size_t)(v2.x & 0x1FFFFu) * 16 + f]);
    float c3 = __uint_as_float(v3.y) * bf2f(x16b[(size_t)(v3.x & 0x1FFFFu) * 16 + f]);
    bool sm;
    sm = (i0 == cid); if (!sm && cid >= 0) atomicAdd(&sacc[cid * 16 + f], sum);
    sum = sm ? sum + c0 : c0; cid = i0;
    sm = (i1 == cid); if (!sm) atomicAdd(&sacc[cid * 16 + f], sum);
    sum = sm ? sum + c1 : c1; cid = i1;
    sm = (i2 == cid); if (!sm) atomicAdd(&sacc[cid * 16 + f], sum);
    sum = sm ? sum + c2 : c2; cid = i2;
    sm = (i3 == cid); if (!sm) atomicAdd(&sacc[cid * 16 + f], sum);
    sum = sm ? sum + c3 : c3; cid = i3;
  }
  for (; e < ge; e++) {
    uint2 v0 = csr8[e];
    int i0 = (int)(v0.x >> 17) - lbase;
    float c0 = __uint_as_float(v0.y) * bf2f(x16b[(size_t)(v0.x & 0x1FFFFu) * 16 + f]);
    bool sm = (i0 == cid);
    if (!sm && cid >= 0) atomicAdd(&sacc[cid * 16 + f], sum);
    sum = sm ? sum + c0 : c0; cid = i0;
  }
  if (cid >= 0) atomicAdd(&sacc[cid * 16 + f], sum);
  __syncthreads();
  for (int i = t; i < NN1 * 16; i += 256) {
    float di = sdinv[i >> 4];
    sacc[i] = di * (sacc[i] + di * bf2f(sx[i]));
  }
  __syncthreads();
  int ff = t & 63, wv = t >> 6;
  float S = 0.f, Q = 0.f;
  for (int i = 0; i < 16; i++) {
    int nd = wv + 4 * i;
    if (nd < nn) {
      float o = bs[ff];
#pragma unroll
      for (int k = 0; k < F0; k++) o += sacc[nd * 16 + k] * Ws[k * F1 + ff];
      h[(size_t)(n0 + nd) * F1 + ff] = f2bf(o);
      S += o; Q += o * o;
    }
  }
  sS[wv][ff] = S; sQ[wv][ff] = Q;
  __syncthreads();
  if (t < 64)
    pbn[(size_t)bid * 64 + t] =
        make_float2(sS[0][t] + sS[1][t] + sS[2][t] + sS[3][t],
                    sQ[0][t] + sQ[1][t] + sQ[2][t] + sQ[3][t]);
}

// mid-level BN reduction over nrows partial rows
__global__ void k_bn_mid(const float2* __restrict__ pbn, float2* __restrict__ pbn2, int nrows) {
  __shared__ float sS[4][64], sQ[4][64];
  int t = threadIdx.x;
  int f = t & 63, g = t >> 6;
  int rpb = (nrows + 63) / 64;
  int b0 = blockIdx.x * rpb;
  int bend = min(nrows, b0 + rpb);
  float S = 0.f, Q = 0.f;
  for (int b = b0 + g; b < bend; b += 4) {
    float2 v = pbn[(size_t)b * 64 + f];
    S += v.x; Q += v.y;
  }
  sS[g][f] = S; sQ[g][f] = Q;
  __syncthreads();
  if (t < 64)
    pbn2[(size_t)blockIdx.x * 64 + t] =
        make_float2(sS[0][t] + sS[1][t] + sS[2][t] + sS[3][t],
                    sQ[0][t] + sQ[1][t] + sQ[2][t] + sQ[3][t]);
}

__global__ void k_bn_final(const float2* __restrict__ pbn2, const float* __restrict__ gamma,
                           const float* __restrict__ beta, float* __restrict__ scalef,
                           float* __restrict__ shiftf, int n) {
  __shared__ double sS[4][64], sQ[4][64];
  int t = threadIdx.x;
  int f = t & 63, g = t >> 6;
  double S = 0.0, Q = 0.0;
  for (int b = g; b < 64; b += 4) {
    float2 v = pbn2[(size_t)b * 64 + f];
    S += v.x; Q += v.y;
  }
  sS[g][f] = S; sQ[g][f] = Q;
  __syncthreads();
  if (t < 64) {
    double SS = sS[0][t] + sS[1][t] + sS[2][t] + sS[3][t];
    double QQ = sQ[0][t] + sQ[1][t] + sQ[2][t] + sQ[3][t];
    double mean = SS / (double)n;
    double var = QQ / (double)n - mean * mean;
    if (var < 0.0) var = 0.0;
    float scale = gamma[t] * (float)(1.0 / sqrt(var + 1e-5));
    scalef[t] = scale;
    shiftf[t] = beta[t] - (float)mean * scale;
  }
}

// ---------------- hn = bf16(relu(bn(h))) elementwise ----------------
__global__ void k_hn(const unsigned short* __restrict__ h, const float* __restrict__ scalef,
                     const float* __restrict__ shiftf, unsigned short* __restrict__ hn,
                     int total4) {
  __shared__ float ssc[64], ssf[64];
  int t = threadIdx.x;
  if (t < 64) { ssc[t] = scalef[t]; ssf[t] = shiftf[t]; }
  __syncthreads();
  int idx = blockIdx.x * blockDim.x + t;
  int stride = gridDim.x * blockDim.x;
  const unsigned long long* hp = (const unsigned long long*)h;
  unsigned long long* hnp = (unsigned long long*)hn;
  for (int i = idx; i < total4; i += stride) {
    unsigned long long vv = hp[i];
    int f0 = (i * 4) & 63;
    float a = fmaxf(fmaf(bf2f_lo((unsigned)vv), ssc[f0 + 0], ssf[f0 + 0]), 0.f);
    float b = fmaxf(fmaf(bf2f_hi((unsigned)vv), ssc[f0 + 1], ssf[f0 + 1]), 0.f);
    float c = fmaxf(fmaf(bf2f_lo((unsigned)(vv >> 32)), ssc[f0 + 2], ssf[f0 + 2]), 0.f);
    float d = fmaxf(fmaf(bf2f_hi((unsigned)(vv >> 32)), ssc[f0 + 3], ssf[f0 + 3]), 0.f);
    hnp[i] = (unsigned long long)f2bf(a) | ((unsigned long long)f2bf(b) << 16) |
             ((unsigned long long)f2bf(c) << 32) | ((unsigned long long)f2bf(d) << 48);
  }
}

// -------- layer-2 aggregation: wave-per-node, 8 chains, lean inner loop (hn input) --------
__global__ void k_agg2(const unsigned short* __restrict__ hn, const int* __restrict__ offs,
                       const uint2* __restrict__ csr8, const float* __restrict__ dinv,
                       float* __restrict__ agg2, int n) {
  __shared__ unsigned s_soff[4][64];
  __shared__ float    s_nrm[4][64];
  int t = threadIdx.x;
  int wv = t >> 6;
  int lane = t & 63;
  int wid = (blockIdx.x * blockDim.x + t) >> 6;
  if (wid >= n) return;
  float di = dinv[wid];
  float a0 = di * bf2f(hn[(size_t)wid * F1 + lane]);   // self loop (outer di applied at end)
  float a1 = 0.f, a2 = 0.f, a3 = 0.f, a4 = 0.f, a5 = 0.f, a6 = 0.f, a7 = 0.f;
  int s = offs[wid], e = offs[wid + 1];
  for (int base = s; base < e; base += 64) {
    int m = e - base; if (m > 64) m = 64;
    if (lane < m) {
      uint2 v = csr8[base + lane];
      s_soff[wv][lane] = (v.x & 0x1FFFFu) * 64u;
      s_nrm[wv][lane] = __uint_as_float(v.y);
    } else {
      s_soff[wv][lane] = 0u;
      s_nrm[wv][lane] = 0.f;
    }
    int mp = (m + 7) & ~7;
    for (int j = 0; j < mp; j += 8) {
      unsigned o0 = s_soff[wv][j + 0], o1 = s_soff[wv][j + 1];
      unsigned o2 = s_soff[wv][j + 2], o3 = s_soff[wv][j + 3];
      unsigned o4 = s_soff[wv][j + 4], o5 = s_soff[wv][j + 5];
      unsigned o6 = s_soff[wv][j + 6], o7 = s_soff[wv][j + 7];
      float m0 = s_nrm[wv][j + 0], m1 = s_nrm[wv][j + 1];
      float m2 = s_nrm[wv][j + 2], m3 = s_nrm[wv][j + 3];
      float m4 = s_nrm[wv][j + 4], m5 = s_nrm[wv][j + 5];
      float m6 = s_nrm[wv][j + 6], m7 = s_nrm[wv][j + 7];
      a0 += m0 * bf2f(hn[(size_t)o0 + lane]);
      a1 += m1 * bf2f(hn[(size_t)o1 + lane]);
      a2 += m2 * bf2f(hn[(size_t)o2 + lane]);
      a3 += m3 * bf2f(hn[(size_t)o3 + lane]);
      a4 += m4 * bf2f(hn[(size_t)o4 + lane]);
      a5 += m5 * bf2f(hn[(size_t)o5 + lane]);
      a6 += m6 * bf2f(hn[(size_t)o6 + lane]);
      a7 += m7 * bf2f(hn[(size_t)o7 + lane]);
    }
  }
  agg2[(size_t)wid * F1 + lane] =
      di * (((a0 + a1) + (a2 + a3)) + ((a4 + a5) + (a6 + a7)));
}

// ---------------- out = agg2 @ W2 + b2, register-tiled GEMM ----------------
__global__ __launch_bounds__(256) void k_gemm2(const float* __restrict__ agg2,
                                               const float* __restrict__ W2,
                                               const float* __restrict__ b2,
                                               float* __restrict__ out, int n) {
  __shared__ float Ws[F1 * F2];
  __shared__ float As[F1][TN2];
  int t = threadIdx.x;
  for (int i = t; i < F1 * F2 / 4; i += 256) ((float4*)Ws)[i] = ((const float4*)W2)[i];
  int nb = blockIdx.x * TN2;
  int node = t & 127;
  int kh = (t >> 7) * 32;
  int gnode = nb + node;
  if (gnode < n) {
    const float4* src = (const float4*)(agg2 + (size_t)gnode * F1 + kh);
#pragma unroll
    for (int j = 0; j < 8; j++) {
      float4 v = src[j];
      As[kh + j * 4 + 0][node] = v.x;
      As[kh + j * 4 + 1][node] = v.y;
      As[kh + j * 4 + 2][node] = v.z;
      As[kh + j * 4 + 3][node] = v.w;
    }
  } else {
#pragma unroll
    for (int j = 0; j < 8; j++) {
      As[kh + j * 4 + 0][node] = 0.f;
      As[kh + j * 4 + 1][node] = 0.f;
      As[kh + j * 4 + 2][node] = 0.f;
      As[kh + j * 4 + 3][node] = 0.f;
    }
  }
  __syncthreads();

  int f0 = (t & 15) * 8;
  int n0 = (t >> 4) * 8;
  float acc[8][8];
  float bv[8];
#pragma unroll
  for (int j = 0; j < 8; j++) bv[j] = b2[f0 + j];
#pragma unroll
  for (int i = 0; i < 8; i++)
#pragma unroll
    for (int j = 0; j < 8; j++) acc[i][j] = bv[j];

#pragma unroll 4
  for (int k = 0; k < F1; k++) {
    float4 a0 = *(const float4*)&As[k][n0];
    float4 a1 = *(const float4*)&As[k][n0 + 4];
    float4 w0 = *(const float4*)&Ws[k * F2 + f0];
    float4 w1 = *(const float4*)&Ws[k * F2 + f0 + 4];
    float a[8] = {a0.x, a0.y, a0.z, a0.w, a1.x, a1.y, a1.z, a1.w};
    float w[8] = {w0.x, w0.y, w0.z, w0.w, w1.x, w1.y, w1.z, w1.w};
#pragma unroll
    for (int i = 0; i < 8; i++)
#pragma unroll
      for (int j = 0; j < 8; j++) acc[i][j] += a[i] * w[j];
  }

#pragma unroll
  for (int i = 0; i < 8; i++) {
    int gi = nb + n0 + i;
    if (gi < n) {
      float4 o0 = {acc[i][0], acc[i][1], acc[i][2], acc[i][3]};
      float4 o1 = {acc[i][4], acc[i][5], acc[i][6], acc[i][7]};
      *(float4*)&out[(size_t)gi * F2 + f0] = o0;
      *(float4*)&out[(size_t)gi * F2 + f0 + 4] = o1;
    }
  }
}

extern "C" void kernel_launch(void* const* d_in, const int* in_sizes, int n_in,
                              void* d_out, int out_size, void* d_ws, size_t ws_size,
                              hipStream_t stream) {
  const float* x     = (const float*)d_in[0];
  const int*   ei    = (const int*)d_in[1];
  const float* ew    = (const float*)d_in[2];
  const float* W1    = (const float*)d_in[3];
  const float* b1    = (const float*)d_in[4];
  const float* gamma = (const float*)d_in[5];
  const float* beta  = (const float*)d_in[6];
  const float* W2    = (const float*)d_in[7];
  const float* b2    = (const float*)d_in[8];
  float* out = (float*)d_out;

  int N = in_sizes[0] / F0;
  int E = in_sizes[1] / 2;
  const int* row = ei;
  const int* col = ei + E;
  if (N <= 0) return;

  int CE = (E + CHUNKS - 1) / CHUNKS;
  int RANGES = (N + BPR - 1) / BPR;
  int npad = RANGES * BPR;
  int NBLK = (N + NN1 - 1) / NN1;

  // ---- workspace carve-up (with overlays) ----
  char* p = (char*)d_ws;
  auto alloc = [&](size_t bytes) -> void* {
    void* r = (void*)p;
    p += (bytes + 255) & ~(size_t)255;
    return r;
  };
  size_t partial_bytes = ((size_t)RANGES * CHUNKS * WPR * 4 + 255) & ~(size_t)255;
  size_t rel_bytes     = (size_t)CHUNKS * npad * 2;
  size_t h_bytes       = (size_t)N * F1 * 2;
  size_t region_bytes  = partial_bytes + rel_bytes;
  if (h_bytes > region_bytes) region_bytes = h_bytes;

  float*          dinv    = (float*)alloc((size_t)N * 4);
  int*            cnt     = (int*)alloc((size_t)N * 4);
  int*            offs    = (int*)alloc((size_t)(N + 1) * 4);
  int             NB      = (N + 1023) / 1024;
  int*            bsum    = (int*)alloc((size_t)NB * 4);
  uint2*          csr8    = (uint2*)alloc((size_t)E * 8);
  char*           region  = (char*)alloc(region_bytes);
  unsigned*       partial = (unsigned*)region;
  unsigned short* rel     = (unsigned short*)(region + partial_bytes);
  unsigned short* h       = (unsigned short*)region;     // after fill2
  unsigned short* x16b    = (unsigned short*)alloc((size_t)N * 16 * 2);
  unsigned short* hn      = (unsigned short*)alloc((size_t)N * F1 * 2);
  float*          agg2    = (float*)alloc((size_t)N * F1 * 4);   // hosts buckets pre-fill
  float2*         pbn     = (float2*)alloc((size_t)NBLK * 64 * 8);
  float2*         pbn2    = (float2*)alloc((size_t)64 * 64 * 8);
  float*          scalef  = (float*)alloc(64 * 4);
  float*          shiftf  = (float*)alloc(64 * 4);
  int*            bcnt    = (int*)alloc((size_t)NBKT * 4);
  int*            boff    = (int*)alloc((size_t)(NBKT + 1) * 4);
  size_t bloc_bytes = (((size_t)E * 2) + 255) & ~(size_t)255;
  unsigned short* bloc = (unsigned short*)agg2;
  uint2*          brw  = (uint2*)((char*)agg2 + bloc_bytes);
  (void)ws_size; (void)n_in; (void)out_size;

  int bW  = (N + 3) / 4;
  int bG2 = (N + TN2 - 1) / TN2;
  int gRC = CHUNKS * RANGES;

  k_pad<<<(N * 16 + 255) / 256, 256, 0, stream>>>(x, x16b, N);
  k_cnt8<<<CHUNKS * 4, 1024, 0, stream>>>(col, bcnt, E, CE);
  k_scan8<<<1, 1024, 0, stream>>>(bcnt, boff);
  k_scatter<<<CHUNKS * 4, 1024, 0, stream>>>(col, row, ew, boff, bloc, brw, E, CE);
  k_hist2<<<gRC, 1024, 0, stream>>>(bloc, boff, partial, RANGES);
  k_colprefix<<<(N + 255) / 256, 256, 0, stream>>>(partial, rel, cnt, N, npad);
  k_scan1<<<NB, 1024, 0, stream>>>(cnt, offs, bsum, N);
  k_scan2<<<1, 256, 0, stream>>>(bsum, NB);
  k_scan3<<<NB, 1024, 0, stream>>>(offs, bsum, N, E);
  k_fill2<<<gRC, 1024, 0, stream>>>(bloc, brw, boff, offs, rel, csr8, N, npad, RANGES);
  k_deg2<<<bW, 256, 0, stream>>>(csr8, offs, dinv, N);
  k_norm<<<(E + 255) / 256, 256, 0, stream>>>(csr8, dinv, E);
  k_agg1e<<<NBLK, 256, 0, stream>>>(x16b, offs, csr8, dinv, W1, b1, h, pbn, N);
  k_bn_mid<<<64, 256, 0, stream>>>(pbn, pbn2, NBLK);
  k_bn_final<<<1, 256, 0, stream>>>(pbn2, gamma, beta, scalef, shiftf, N);
  k_hn<<<2048, 256, 0, stream>>>(h, scalef, shiftf, hn, N * F1 / 4);
  k_agg2<<<bW, 256, 0, stream>>>(hn, offs, csr8, dinv, agg2, N);
  k_gemm2<<<bG2, 256, 0, stream>>>(agg2, W2, b2, out, N);
}

// Round 14
// 212.204 us; speedup vs baseline: 1.1600x; 1.0089x over previous
//
#include <hip/hip_runtime.h>

#define F0 11
#define F1 64
#define F2 128
#define TN2 128      // nodes per block in k_gemm2

#define CHUNKS 64
#define BPR 12544    // bins per range; %64==0; N <= 8*BPR = 100352 (src fits 17 bits)
#define WPR (BPR / 2)
#define NBKT (CHUNKS * 8 * 4)
#define NN1 64       // nodes per block in edge-parallel agg1

// bf16 helpers (round-to-nearest-even)
__device__ __forceinline__ unsigned short f2bf(float v) {
  unsigned u = __float_as_uint(v);
  unsigned r = u + 0x7FFFu + ((u >> 16) & 1u);
  return (unsigned short)(r >> 16);
}
__device__ __forceinline__ float bf2f(unsigned short s) {
  return __uint_as_float(((unsigned)s) << 16);
}
__device__ __forceinline__ float bf2f_lo(unsigned v) { return __uint_as_float(v << 16); }
__device__ __forceinline__ float bf2f_hi(unsigned v) { return __uint_as_float(v & 0xFFFF0000u); }

// ---------------- pad x -> x16b (16 bf16 per row); zero wdeg ----------------
__global__ void k_pad(const float* __restrict__ x, unsigned short* __restrict__ x16b,
                      float* __restrict__ wdeg, int n) {
  int i = blockIdx.x * blockDim.x + threadIdx.x;
  if (i < n) wdeg[i] = 0.f;
  if (i >= n * 16) return;
  int r = i >> 4, f = i & 15;
  x16b[i] = (f < F0) ? f2bf(x[(size_t)r * F0 + f]) : (unsigned short)0;
}

// ---------------- per-(quarter-chunk), per-range edge counts ----------------
__global__ __launch_bounds__(1024) void k_cnt8(const int* __restrict__ col,
                                               int* __restrict__ bcnt, int E, int CE) {
  __shared__ int scnt[16][8];
  int bid = blockIdx.x;
  int c = bid >> 2, q = bid & 3;
  int e0 = c * CE, e1 = min(E, e0 + CE);
  int S = (CE + 3) >> 2;
  int s0 = e0 + q * S, s1 = min(e1, s0 + S);
  int t = threadIdx.x, wv = t >> 6, lane = t & 63;
  int cr[8] = {0, 0, 0, 0, 0, 0, 0, 0};
  for (int e = s0 + t; e < s1; e += 1024) {
    int r = col[e] / BPR;
#pragma unroll
    for (int rr = 0; rr < 8; rr++) cr[rr] += (r == rr) ? 1 : 0;
  }
#pragma unroll
  for (int rr = 0; rr < 8; rr++) {
    int v = cr[rr];
#pragma unroll
    for (int d = 32; d > 0; d >>= 1) v += __shfl_down(v, d);
    if (lane == 0) scnt[wv][rr] = v;
  }
  __syncthreads();
  if (t < 8) {
    int s = 0;
    for (int i = 0; i < 16; i++) s += scnt[i][t];
    bcnt[(c * 8 + t) * 4 + q] = s;
  }
}

// ---------------- exclusive scan of 2048 bucket counts -> boff ----------------
__global__ void k_scan8(const int* __restrict__ bcnt, int* __restrict__ boff) {
  __shared__ int s[1024];
  int t = threadIdx.x;
  int v0 = bcnt[2 * t], v1 = bcnt[2 * t + 1];
  int pv = v0 + v1;
  s[t] = pv;
  __syncthreads();
  for (int d = 1; d < 1024; d <<= 1) {
    int x = (t >= d) ? s[t - d] : 0;
    __syncthreads();
    s[t] += x;
    __syncthreads();
  }
  int ex = s[t] - pv;
  boff[2 * t] = ex;
  boff[2 * t + 1] = ex + v0;
  if (t == 1023) boff[2048] = s[1023];
}

// ---------------- scatter edges into private buckets; LDS cursors ----------------
__global__ __launch_bounds__(1024) void k_scatter(const int* __restrict__ col,
                                                  const int* __restrict__ row,
                                                  const float* __restrict__ w,
                                                  const int* __restrict__ boff,
                                                  unsigned short* __restrict__ bloc,
                                                  uint2* __restrict__ brw, int E, int CE) {
  __shared__ int cur[8];
  int bid = blockIdx.x;
  int c = bid >> 2, q = bid & 3;
  int t = threadIdx.x;
  if (t < 8) cur[t] = boff[(c * 8 + t) * 4 + q];
  __syncthreads();
  int e0 = c * CE, e1 = min(E, e0 + CE);
  int S = (CE + 3) >> 2;
  int s0 = e0 + q * S, s1 = min(e1, s0 + S);
  for (int e = s0 + t; e < s1; e += 1024) {
    int b = col[e];
    int r = b / BPR;
    int pos = atomicAdd(&cur[r], 1);
    bloc[pos] = (unsigned short)(b - r * BPR);
    brw[pos] = make_uint2((unsigned)row[e], __float_as_uint(w[e]));
  }
}

// ------- histogram + weighted-degree from bucket data: partial[] + atomic wdeg dump -------
__global__ __launch_bounds__(1024) void k_hist2(const unsigned short* __restrict__ bloc,
                                                const uint2* __restrict__ brw,
                                                const int* __restrict__ boff,
                                                unsigned* __restrict__ partial,
                                                float* __restrict__ wdeg,
                                                int N, int ranges) {
  __shared__ unsigned lds[WPR];       // 25,088 B packed u16 counts
  __shared__ float swdeg[BPR];        // 50,176 B weighted-degree partials
  int r = blockIdx.x % ranges;
  int c = blockIdx.x / ranges;
  int t = threadIdx.x;
  for (int i = t; i < WPR; i += 1024) lds[i] = 0;
  for (int i = t; i < BPR; i += 1024) swdeg[i] = 0.f;
  __syncthreads();
  int s0 = boff[(c * 8 + r) * 4], s1 = boff[(c * 8 + r) * 4 + 4];
  for (int i = s0 + t; i < s1; i += 1024) {
    int local = bloc[i];
    float wv = __uint_as_float(brw[i].y);
    atomicAdd(&lds[local >> 1], 1u << (16 * (local & 1)));
    atomicAdd(&swdeg[local], wv);
  }
  __syncthreads();
  unsigned* dst = partial + ((size_t)r * CHUNKS + c) * WPR;
  for (int i = t; i < WPR; i += 1024) dst[i] = lds[i];
  int lo = r * BPR;
  int hi = min(N, lo + BPR);
  for (int i = lo + t; i < hi; i += 1024) {
    float v = swdeg[i - lo];
    if (v != 0.f) atomicAdd(&wdeg[i], v);
  }
}

// ---------------- dinv = rsqrt(1 + wdeg) ----------------
__global__ void k_dinv(const float* __restrict__ wdeg, float* __restrict__ dinv, int n) {
  int i = blockIdx.x * blockDim.x + threadIdx.x;
  if (i < n) dinv[i] = rsqrtf(1.0f + wdeg[i]);
}

// ---------------- per-bin prefix over chunks ----------------
__global__ void k_colprefix(const unsigned* __restrict__ partial,
                            unsigned short* __restrict__ rel,
                            int* __restrict__ cnt, int N, int npad) {
  int bin = blockIdx.x * blockDim.x + threadIdx.x;
  if (bin >= N) return;
  int r = bin / BPR, local = bin % BPR;
  int word = local >> 1, sh = 16 * (local & 1);
  const unsigned* p = partial + (size_t)r * CHUNKS * WPR + word;
  unsigned acc = 0;
  for (int c = 0; c < CHUNKS; c++) {
    unsigned v = (p[(size_t)c * WPR] >> sh) & 0xFFFFu;
    rel[(size_t)c * npad + bin] = (unsigned short)acc;
    acc += v;
  }
  cnt[bin] = (int)acc;
}

// ---------------- exclusive scan of cnt -> offs ----------------
__global__ void k_scan1(const int* __restrict__ cnt, int* __restrict__ offs,
                        int* __restrict__ bsum, int n) {
  __shared__ int s[1024];
  int tid = threadIdx.x;
  int i = blockIdx.x * 1024 + tid;
  int v = (i < n) ? cnt[i] : 0;
  s[tid] = v;
  __syncthreads();
  for (int d = 1; d < 1024; d <<= 1) {
    int t = (tid >= d) ? s[tid - d] : 0;
    __syncthreads();
    s[tid] += t;
    __syncthreads();
  }
  if (i < n) offs[i] = s[tid] - v;
  if (tid == 1023) bsum[blockIdx.x] = s[1023];
}

__global__ void k_scan2(int* __restrict__ bsum, int nb) {
  __shared__ int s[256];
  __shared__ int carry;
  int t = threadIdx.x;
  if (t == 0) carry = 0;
  __syncthreads();
  for (int base = 0; base < nb; base += 256) {
    int v = (base + t < nb) ? bsum[base + t] : 0;
    s[t] = v;
    __syncthreads();
    for (int d = 1; d < 256; d <<= 1) {
      int x = (t >= d) ? s[t - d] : 0;
      __syncthreads();
      s[t] += x;
      __syncthreads();
    }
    int total = s[255];
    if (base + t < nb) bsum[base + t] = carry + s[t] - v;
    __syncthreads();
    if (t == 0) carry += total;
    __syncthreads();
  }
}

__global__ void k_scan3(int* __restrict__ offs, const int* __restrict__ bsum,
                        int n, int total) {
  int i = blockIdx.x * 1024 + threadIdx.x;
  if (i < n) offs[i] += bsum[blockIdx.x];
  if (i == 0) offs[n] = total;
}

// --- CSR fill from buckets; pack local<<17 | src; y = dinv[src]*w (normalized at write) ----
__global__ __launch_bounds__(1024) void k_fill2(const unsigned short* __restrict__ bloc,
                                                const uint2* __restrict__ brw,
                                                const int* __restrict__ boff,
                                                const int* __restrict__ offs,
                                                const unsigned short* __restrict__ rel,
                                                const float* __restrict__ dinv,
                                                uint2* __restrict__ csr8,
                                                int N, int npad, int ranges) {
  __shared__ unsigned cur[WPR];
  int r = blockIdx.x % ranges;
  int c = blockIdx.x / ranges;
  int lo = r * BPR;
  int hi = min(N, lo + BPR);
  int t = threadIdx.x;
  const unsigned* rsrc = (const unsigned*)(rel + (size_t)c * npad + lo);
  int nw = (hi - lo + 1) >> 1;
  for (int i = t; i < nw; i += 1024) cur[i] = rsrc[i];
  __syncthreads();
  int s0 = boff[(c * 8 + r) * 4], s1 = boff[(c * 8 + r) * 4 + 4];
  for (int i = s0 + t; i < s1; i += 1024) {
    int local = bloc[i];
    int sh = 16 * (local & 1);
    unsigned old = atomicAdd(&cur[local >> 1], 1u << sh);
    unsigned myrel = (old >> sh) & 0xFFFFu;
    int pos = offs[lo + local] + (int)myrel;
    uint2 b = brw[i];
    float nm = dinv[b.x] * __uint_as_float(b.y);
    csr8[pos] = make_uint2(b.x | ((unsigned)local << 17), __float_as_uint(nm));
  }
}

// ------- edge-parallel layer-1: segmented-reduce into LDS + fused W1 MLP + BN partials -----
__global__ __launch_bounds__(256) void k_agg1e(const unsigned short* __restrict__ x16b,
                                               const int* __restrict__ offs,
                                               const uint2* __restrict__ csr8,
                                               const float* __restrict__ dinv,
                                               const float* __restrict__ W1,
                                               const float* __restrict__ b1,
                                               unsigned short* __restrict__ h,
                                               float2* __restrict__ pbn, int N) {
  __shared__ float Ws[F0 * F1];
  __shared__ float bs[F1];
  __shared__ float sacc[NN1 * 16];
  __shared__ unsigned short sx[NN1 * 16];
  __shared__ float sdinv[NN1];
  __shared__ float sS[4][64], sQ[4][64];
  int t = threadIdx.x;
  int bid = blockIdx.x;
  int n0 = bid * NN1;
  int nn = min(NN1, N - n0);
  int lbase = n0 - (n0 / BPR) * BPR;
  for (int i = t; i < F0 * F1; i += 256) Ws[i] = W1[i];
  if (t < F1) bs[t] = b1[t];
  ((uint2*)sx)[t] = ((const uint2*)(x16b + (size_t)n0 * 16))[t];
  if (t < NN1) sdinv[t] = (t < nn) ? dinv[n0 + t] : 0.f;
  for (int i = t; i < NN1 * 16; i += 256) sacc[i] = 0.f;
  __syncthreads();
  int ebase = offs[n0], eend = offs[n0 + nn];
  int slot = t >> 4, f = t & 15;
  int nsub = (eend - ebase + 15) >> 4;
  int gs = ebase + slot * nsub;
  int ge = min(eend, gs + nsub);
  float sum = 0.f;
  int cid = -1;
  int e = gs;
  for (; e + 4 <= ge; e += 4) {
    uint2 v0 = csr8[e], v1 = csr8[e + 1], v2 = csr8[e + 2], v3 = csr8[e + 3];
    int i0 = (int)(v0.x >> 17) - lbase, i1 = (int)(v1.x >> 17) - lbase;
    int i2 = (int)(v2.x >> 17) - lbase, i3 = (int)(v3.x >> 17) - lbase;
    float c0 = __uint_as_float(v0.y) * bf2f(x16b[(size_t)(v0.x & 0x1FFFFu) * 16 + f]);
    float c1 = __uint_as_float(v1.y) * bf2f(x16b[(size_t)(v1.x & 0x1FFFFu) * 16 + f]);
    float c2 = __uint_as_float(v2.y) * bf2f(x16b[(size_t)(v2.x & 0x1FFFFu) * 16 + f]);
    float c3 = __uint_as_float(v3.y) * bf2f(x16b[(size_t)(v3.x & 0x1FFFFu) * 16 + f]);
    bool sm;
    sm = (i0 == cid); if (!sm && cid >= 0) atomicAdd(&sacc[cid * 16 + f], sum);
    sum = sm ? sum + c0 : c0; cid = i0;
    sm = (i1 == cid); if (!sm) atomicAdd(&sacc[cid * 16 + f], sum);
    sum = sm ? sum + c1 : c1; cid = i1;
    sm = (i2 == cid); if (!sm) atomicAdd(&sacc[cid * 16 + f], sum);
    sum = sm ? sum + c2 : c2; cid = i2;
    sm = (i3 == cid); if (!sm) atomicAdd(&sacc[cid * 16 + f], sum);
    sum = sm ? sum + c3 : c3; cid = i3;
  }
  for (; e < ge; e++) {
    uint2 v0 = csr8[e];
    int i0 = (int)(v0.x >> 17) - lbase;
    float c0 = __uint_as_float(v0.y) * bf2f(x16b[(size_t)(v0.x & 0x1FFFFu) * 16 + f]);
    bool sm = (i0 == cid);
    if (!sm && cid >= 0) atomicAdd(&sacc[cid * 16 + f], sum);
    sum = sm ? sum + c0 : c0; cid = i0;
  }
  if (cid >= 0) atomicAdd(&sacc[cid * 16 + f], sum);
  __syncthreads();
  for (int i = t; i < NN1 * 16; i += 256) {
    float di = sdinv[i >> 4];
    sacc[i] = di * (sacc[i] + di * bf2f(sx[i]));
  }
  __syncthreads();
  int ff = t & 63, wv = t >> 6;
  float S = 0.f, Q = 0.f;
  for (int i = 0; i < 16; i++) {
    int nd = wv + 4 * i;
    if (nd < nn) {
      float o = bs[ff];
#pragma unroll
      for (int k = 0; k < F0; k++) o += sacc[nd * 16 + k] * Ws[k * F1 + ff];
      h[(size_t)(n0 + nd) * F1 + ff] = f2bf(o);
      S += o; Q += o * o;
    }
  }
  sS[wv][ff] = S; sQ[wv][ff] = Q;
  __syncthreads();
  if (t < 64)
    pbn[(size_t)bid * 64 + t] =
        make_float2(sS[0][t] + sS[1][t] + sS[2][t] + sS[3][t],
                    sQ[0][t] + sQ[1][t] + sQ[2][t] + sQ[3][t]);
}

// mid-level BN reduction over nrows partial rows
__global__ void k_bn_mid(const float2* __restrict__ pbn, float2* __restrict__ pbn2, int nrows) {
  __shared__ float sS[4][64], sQ[4][64];
  int t = threadIdx.x;
  int f = t & 63, g = t >> 6;
  int rpb = (nrows + 63) / 64;
  int b0 = blockIdx.x * rpb;
  int bend = min(nrows, b0 + rpb);
  float S = 0.f, Q = 0.f;
  for (int b = b0 + g; b < bend; b += 4) {
    float2 v = pbn[(size_t)b * 64 + f];
    S += v.x; Q += v.y;
  }
  sS[g][f] = S; sQ[g][f] = Q;
  __syncthreads();
  if (t < 64)
    pbn2[(size_t)blockIdx.x * 64 + t] =
        make_float2(sS[0][t] + sS[1][t] + sS[2][t] + sS[3][t],
                    sQ[0][t] + sQ[1][t] + sQ[2][t] + sQ[3][t]);
}

__global__ void k_bn_final(const float2* __restrict__ pbn2, const float* __restrict__ gamma,
                           const float* __restrict__ beta, float* __restrict__ scalef,
                           float* __restrict__ shiftf, int n) {
  __shared__ double sS[4][64], sQ[4][64];
  int t = threadIdx.x;
  int f = t & 63, g = t >> 6;
  double S = 0.0, Q = 0.0;
  for (int b = g; b < 64; b += 4) {
    float2 v = pbn2[(size_t)b * 64 + f];
    S += v.x; Q += v.y;
  }
  sS[g][f] = S; sQ[g][f] = Q;
  __syncthreads();
  if (t < 64) {
    double SS = sS[0][t] + sS[1][t] + sS[2][t] + sS[3][t];
    double QQ = sQ[0][t] + sQ[1][t] + sQ[2][t] + sQ[3][t];
    double mean = SS / (double)n;
    double var = QQ / (double)n - mean * mean;
    if (var < 0.0) var = 0.0;
    float scale = gamma[t] * (float)(1.0 / sqrt(var + 1e-5));
    scalef[t] = scale;
    shiftf[t] = beta[t] - (float)mean * scale;
  }
}

// ---------------- hn = bf16(relu(bn(h))) elementwise ----------------
__global__ void k_hn(const unsigned short* __restrict__ h, const float* __restrict__ scalef,
                     const float* __restrict__ shiftf, unsigned short* __restrict__ hn,
                     int total4) {
  __shared__ float ssc[64], ssf[64];
  int t = threadIdx.x;
  if (t < 64) { ssc[t] = scalef[t]; ssf[t] = shiftf[t]; }
  __syncthreads();
  int idx = blockIdx.x * blockDim.x + t;
  int stride = gridDim.x * blockDim.x;
  const unsigned long long* hp = (const unsigned long long*)h;
  unsigned long long* hnp = (unsigned long long*)hn;
  for (int i = idx; i < total4; i += stride) {
    unsigned long long vv = hp[i];
    int f0 = (i * 4) & 63;
    float a = fmaxf(fmaf(bf2f_lo((unsigned)vv), ssc[f0 + 0], ssf[f0 + 0]), 0.f);
    float b = fmaxf(fmaf(bf2f_hi((unsigned)vv), ssc[f0 + 1], ssf[f0 + 1]), 0.f);
    float c = fmaxf(fmaf(bf2f_lo((unsigned)(vv >> 32)), ssc[f0 + 2], ssf[f0 + 2]), 0.f);
    float d = fmaxf(fmaf(bf2f_hi((unsigned)(vv >> 32)), ssc[f0 + 3], ssf[f0 + 3]), 0.f);
    hnp[i] = (unsigned long long)f2bf(a) | ((unsigned long long)f2bf(b) << 16) |
             ((unsigned long long)f2bf(c) << 32) | ((unsigned long long)f2bf(d) << 48);
  }
}

// -------- layer-2 aggregation: wave-per-node, 8 chains, bf16 output --------
__global__ void k_agg2(const unsigned short* __restrict__ hn, const int* __restrict__ offs,
                       const uint2* __restrict__ csr8, const float* __restrict__ dinv,
                       unsigned short* __restrict__ agg2b, int n) {
  __shared__ unsigned s_soff[4][64];
  __shared__ float    s_nrm[4][64];
  int t = threadIdx.x;
  int wv = t >> 6;
  int lane = t & 63;
  int wid = (blockIdx.x * blockDim.x + t) >> 6;
  if (wid >= n) return;
  float di = dinv[wid];
  float a0 = di * bf2f(hn[(size_t)wid * F1 + lane]);   // self loop
  float a1 = 0.f, a2 = 0.f, a3 = 0.f, a4 = 0.f, a5 = 0.f, a6 = 0.f, a7 = 0.f;
  int s = offs[wid], e = offs[wid + 1];
  for (int base = s; base < e; base += 64) {
    int m = e - base; if (m > 64) m = 64;
    if (lane < m) {
      uint2 v = csr8[base + lane];
      s_soff[wv][lane] = (v.x & 0x1FFFFu) * 64u;
      s_nrm[wv][lane] = __uint_as_float(v.y);
    } else {
      s_soff[wv][lane] = 0u;
      s_nrm[wv][lane] = 0.f;
    }
    int mp = (m + 7) & ~7;
    for (int j = 0; j < mp; j += 8) {
      unsigned o0 = s_soff[wv][j + 0], o1 = s_soff[wv][j + 1];
      unsigned o2 = s_soff[wv][j + 2], o3 = s_soff[wv][j + 3];
      unsigned o4 = s_soff[wv][j + 4], o5 = s_soff[wv][j + 5];
      unsigned o6 = s_soff[wv][j + 6], o7 = s_soff[wv][j + 7];
      float m0 = s_nrm[wv][j + 0], m1 = s_nrm[wv][j + 1];
      float m2 = s_nrm[wv][j + 2], m3 = s_nrm[wv][j + 3];
      float m4 = s_nrm[wv][j + 4], m5 = s_nrm[wv][j + 5];
      float m6 = s_nrm[wv][j + 6], m7 = s_nrm[wv][j + 7];
      a0 += m0 * bf2f(hn[(size_t)o0 + lane]);
      a1 += m1 * bf2f(hn[(size_t)o1 + lane]);
      a2 += m2 * bf2f(hn[(size_t)o2 + lane]);
      a3 += m3 * bf2f(hn[(size_t)o3 + lane]);
      a4 += m4 * bf2f(hn[(size_t)o4 + lane]);
      a5 += m5 * bf2f(hn[(size_t)o5 + lane]);
      a6 += m6 * bf2f(hn[(size_t)o6 + lane]);
      a7 += m7 * bf2f(hn[(size_t)o7 + lane]);
    }
  }
  float r = di * (((a0 + a1) + (a2 + a3)) + ((a4 + a5) + (a6 + a7)));
  agg2b[(size_t)wid * F1 + lane] = f2bf(r);
}

// ---------------- out = agg2b(bf16) @ W2 + b2, register-tiled GEMM ----------------
__global__ __launch_bounds__(256) void k_gemm2(const unsigned short* __restrict__ agg2b,
                                               const float* __restrict__ W2,
                                               const float* __restrict__ b2,
                                               float* __restrict__ out, int n) {
  __shared__ float Ws[F1 * F2];
  __shared__ float As[F1][TN2];
  int t = threadIdx.x;
  for (int i = t; i < F1 * F2 / 4; i += 256) ((float4*)Ws)[i] = ((const float4*)W2)[i];
  int nb = blockIdx.x * TN2;
  int node = t & 127;
  int kh = (t >> 7) * 32;
  int gnode = nb + node;
  if (gnode < n) {
    const uint4* src = (const uint4*)(agg2b + (size_t)gnode * F1 + kh);
#pragma unroll
    for (int j = 0; j < 4; j++) {
      uint4 v = src[j];
      As[kh + j * 8 + 0][node] = bf2f_lo(v.x);
      As[kh + j * 8 + 1][node] = bf2f_hi(v.x);
      As[kh + j * 8 + 2][node] = bf2f_lo(v.y);
      As[kh + j * 8 + 3][node] = bf2f_hi(v.y);
      As[kh + j * 8 + 4][node] = bf2f_lo(v.z);
      As[kh + j * 8 + 5][node] = bf2f_hi(v.z);
      As[kh + j * 8 + 6][node] = bf2f_lo(v.w);
      As[kh + j * 8 + 7][node] = bf2f_hi(v.w);
    }
  } else {
#pragma unroll
    for (int j = 0; j < 8; j++) {
      As[kh + j * 4 + 0][node] = 0.f;
      As[kh + j * 4 + 1][node] = 0.f;
      As[kh + j * 4 + 2][node] = 0.f;
      As[kh + j * 4 + 3][node] = 0.f;
    }
  }
  __syncthreads();

  int f0 = (t & 15) * 8;
  int n0 = (t >> 4) * 8;
  float acc[8][8];
  float bv[8];
#pragma unroll
  for (int j = 0; j < 8; j++) bv[j] = b2[f0 + j];
#pragma unroll
  for (int i = 0; i < 8; i++)
#pragma unroll
    for (int j = 0; j < 8; j++) acc[i][j] = bv[j];

#pragma unroll 4
  for (int k = 0; k < F1; k++) {
    float4 a0 = *(const float4*)&As[k][n0];
    float4 a1 = *(const float4*)&As[k][n0 + 4];
    float4 w0 = *(const float4*)&Ws[k * F2 + f0];
    float4 w1 = *(const float4*)&Ws[k * F2 + f0 + 4];
    float a[8] = {a0.x, a0.y, a0.z, a0.w, a1.x, a1.y, a1.z, a1.w};
    float w[8] = {w0.x, w0.y, w0.z, w0.w, w1.x, w1.y, w1.z, w1.w};
#pragma unroll
    for (int i = 0; i < 8; i++)
#pragma unroll
      for (int j = 0; j < 8; j++) acc[i][j] += a[i] * w[j];
  }

#pragma unroll
  for (int i = 0; i < 8; i++) {
    int gi = nb + n0 + i;
    if (gi < n) {
      float4 o0 = {acc[i][0], acc[i][1], acc[i][2], acc[i][3]};
      float4 o1 = {acc[i][4], acc[i][5], acc[i][6], acc[i][7]};
      *(float4*)&out[(size_t)gi * F2 + f0] = o0;
      *(float4*)&out[(size_t)gi * F2 + f0 + 4] = o1;
    }
  }
}

extern "C" void kernel_launch(void* const* d_in, const int* in_sizes, int n_in,
                              void* d_out, int out_size, void* d_ws, size_t ws_size,
                              hipStream_t stream) {
  const float* x     = (const float*)d_in[0];
  const int*   ei    = (const int*)d_in[1];
  const float* ew    = (const float*)d_in[2];
  const float* W1    = (const float*)d_in[3];
  const float* b1    = (const float*)d_in[4];
  const float* gamma = (const float*)d_in[5];
  const float* beta  = (const float*)d_in[6];
  const float* W2    = (const float*)d_in[7];
  const float* b2    = (const float*)d_in[8];
  float* out = (float*)d_out;

  int N = in_sizes[0] / F0;
  int E = in_sizes[1] / 2;
  const int* row = ei;
  const int* col = ei + E;
  if (N <= 0) return;

  int CE = (E + CHUNKS - 1) / CHUNKS;
  int RANGES = (N + BPR - 1) / BPR;
  int npad = RANGES * BPR;
  int NBLK = (N + NN1 - 1) / NN1;

  // ---- workspace carve-up (with overlays) ----
  char* p = (char*)d_ws;
  auto alloc = [&](size_t bytes) -> void* {
    void* r = (void*)p;
    p += (bytes + 255) & ~(size_t)255;
    return r;
  };
  size_t partial_bytes = ((size_t)RANGES * CHUNKS * WPR * 4 + 255) & ~(size_t)255;
  size_t rel_bytes     = (size_t)CHUNKS * npad * 2;
  size_t h_bytes       = (size_t)N * F1 * 2;
  size_t region_bytes  = partial_bytes + rel_bytes;
  if (h_bytes > region_bytes) region_bytes = h_bytes;

  float*          dinv    = (float*)alloc((size_t)N * 4);
  float*          wdeg    = (float*)alloc((size_t)N * 4);
  int*            cnt     = (int*)alloc((size_t)N * 4);
  int*            offs    = (int*)alloc((size_t)(N + 1) * 4);
  int             NB      = (N + 1023) / 1024;
  int*            bsum    = (int*)alloc((size_t)NB * 4);
  uint2*          csr8    = (uint2*)alloc((size_t)E * 8);
  char*           region  = (char*)alloc(region_bytes);
  unsigned*       partial = (unsigned*)region;
  unsigned short* rel     = (unsigned short*)(region + partial_bytes);
  unsigned short* h       = (unsigned short*)region;     // after fill2
  unsigned short* x16b    = (unsigned short*)alloc((size_t)N * 16 * 2);
  unsigned short* hn      = (unsigned short*)alloc((size_t)N * F1 * 2);
  // bucket region also hosts agg2b afterwards
  size_t bloc_bytes = (((size_t)E * 2) + 255) & ~(size_t)255;
  size_t bkt_bytes  = bloc_bytes + (size_t)E * 8;
  size_t a2b_bytes  = (size_t)N * F1 * 2;
  char*           bktreg  = (char*)alloc(bkt_bytes > a2b_bytes ? bkt_bytes : a2b_bytes);
  unsigned short* bloc    = (unsigned short*)bktreg;
  uint2*          brw     = (uint2*)(bktreg + bloc_bytes);
  unsigned short* agg2b   = (unsigned short*)bktreg;     // after fill2 (buckets dead)
  float2*         pbn     = (float2*)alloc((size_t)NBLK * 64 * 8);
  float2*         pbn2    = (float2*)alloc((size_t)64 * 64 * 8);
  float*          scalef  = (float*)alloc(64 * 4);
  float*          shiftf  = (float*)alloc(64 * 4);
  int*            bcnt    = (int*)alloc((size_t)NBKT * 4);
  int*            boff    = (int*)alloc((size_t)(NBKT + 1) * 4);
  (void)ws_size; (void)n_in; (void)out_size;

  int bW  = (N + 3) / 4;
  int bG2 = (N + TN2 - 1) / TN2;
  int gRC = CHUNKS * RANGES;

  k_pad<<<(N * 16 + 255) / 256, 256, 0, stream>>>(x, x16b, wdeg, N);
  k_cnt8<<<CHUNKS * 4, 1024, 0, stream>>>(col, bcnt, E, CE);
  k_scan8<<<1, 1024, 0, stream>>>(bcnt, boff);
  k_scatter<<<CHUNKS * 4, 1024, 0, stream>>>(col, row, ew, boff, bloc, brw, E, CE);
  k_hist2<<<gRC, 1024, 0, stream>>>(bloc, brw, boff, partial, wdeg, N, RANGES);
  k_dinv<<<(N + 255) / 256, 256, 0, stream>>>(wdeg, dinv, N);
  k_colprefix<<<(N + 255) / 256, 256, 0, stream>>>(partial, rel, cnt, N, npad);
  k_scan1<<<NB, 1024, 0, stream>>>(cnt, offs, bsum, N);
  k_scan2<<<1, 256, 0, stream>>>(bsum, NB);
  k_scan3<<<NB, 1024, 0, stream>>>(offs, bsum, N, E);
  k_fill2<<<gRC, 1024, 0, stream>>>(bloc, brw, boff, offs, rel, dinv, csr8, N, npad, RANGES);
  k_agg1e<<<NBLK, 256, 0, stream>>>(x16b, offs, csr8, dinv, W1, b1, h, pbn, N);
  k_bn_mid<<<64, 256, 0, stream>>>(pbn, pbn2, NBLK);
  k_bn_final<<<1, 256, 0, stream>>>(pbn2, gamma, beta, scalef, shiftf, N);
  k_hn<<<2048, 256, 0, stream>>>(h, scalef, shiftf, hn, N * F1 / 4);
  k_agg2<<<bW, 256, 0, stream>>>(hn, offs, csr8, dinv, agg2b, N);
  k_gemm2<<<bG2, 256, 0, stream>>>(agg2b, W2, b2, out, N);
}

// Round 15
// 211.054 us; speedup vs baseline: 1.1663x; 1.0054x over previous
//
#include <hip/hip_runtime.h>

#define F0 11
#define F1 64
#define F2 128
#define TN2 128      // nodes per block in k_gemm2

#define CHUNKS 64
#define BPR 12544    // bins per range; %64==0; N <= 8*BPR = 100352 (src fits 17 bits)
#define WPR (BPR / 2)
#define NBKT (CHUNKS * 8 * 4)
#define NN1 64       // nodes per block in edge-parallel agg1

// bf16 helpers (round-to-nearest-even)
__device__ __forceinline__ unsigned short f2bf(float v) {
  unsigned u = __float_as_uint(v);
  unsigned r = u + 0x7FFFu + ((u >> 16) & 1u);
  return (unsigned short)(r >> 16);
}
__device__ __forceinline__ float bf2f(unsigned short s) {
  return __uint_as_float(((unsigned)s) << 16);
}
__device__ __forceinline__ float bf2f_lo(unsigned v) { return __uint_as_float(v << 16); }
__device__ __forceinline__ float bf2f_hi(unsigned v) { return __uint_as_float(v & 0xFFFF0000u); }

// ---------------- pad x -> x16b (16 bf16 per row); zero wdeg ----------------
__global__ void k_pad(const float* __restrict__ x, unsigned short* __restrict__ x16b,
                      float* __restrict__ wdeg, int n) {
  int i = blockIdx.x * blockDim.x + threadIdx.x;
  if (i < n) wdeg[i] = 0.f;
  if (i >= n * 16) return;
  int r = i >> 4, f = i & 15;
  x16b[i] = (f < F0) ? f2bf(x[(size_t)r * F0 + f]) : (unsigned short)0;
}

// ---------------- per-(quarter-chunk), per-range edge counts ----------------
__global__ __launch_bounds__(1024) void k_cnt8(const int* __restrict__ col,
                                               int* __restrict__ bcnt, int E, int CE) {
  __shared__ int scnt[16][8];
  int bid = blockIdx.x;
  int c = bid >> 2, q = bid & 3;
  int e0 = c * CE, e1 = min(E, e0 + CE);
  int S = (CE + 3) >> 2;
  int s0 = e0 + q * S, s1 = min(e1, s0 + S);
  int t = threadIdx.x, wv = t >> 6, lane = t & 63;
  int cr[8] = {0, 0, 0, 0, 0, 0, 0, 0};
  for (int e = s0 + t; e < s1; e += 1024) {
    int r = col[e] / BPR;
#pragma unroll
    for (int rr = 0; rr < 8; rr++) cr[rr] += (r == rr) ? 1 : 0;
  }
#pragma unroll
  for (int rr = 0; rr < 8; rr++) {
    int v = cr[rr];
#pragma unroll
    for (int d = 32; d > 0; d >>= 1) v += __shfl_down(v, d);
    if (lane == 0) scnt[wv][rr] = v;
  }
  __syncthreads();
  if (t < 8) {
    int s = 0;
    for (int i = 0; i < 16; i++) s += scnt[i][t];
    bcnt[(c * 8 + t) * 4 + q] = s;
  }
}

// ---------------- exclusive scan of 2048 bucket counts -> boff ----------------
__global__ void k_scan8(const int* __restrict__ bcnt, int* __restrict__ boff) {
  __shared__ int s[1024];
  int t = threadIdx.x;
  int v0 = bcnt[2 * t], v1 = bcnt[2 * t + 1];
  int pv = v0 + v1;
  s[t] = pv;
  __syncthreads();
  for (int d = 1; d < 1024; d <<= 1) {
    int x = (t >= d) ? s[t - d] : 0;
    __syncthreads();
    s[t] += x;
    __syncthreads();
  }
  int ex = s[t] - pv;
  boff[2 * t] = ex;
  boff[2 * t + 1] = ex + v0;
  if (t == 1023) boff[2048] = s[1023];
}

// ---------------- scatter edges into private buckets; LDS cursors ----------------
__global__ __launch_bounds__(1024) void k_scatter(const int* __restrict__ col,
                                                  const int* __restrict__ row,
                                                  const float* __restrict__ w,
                                                  const int* __restrict__ boff,
                                                  unsigned short* __restrict__ bloc,
                                                  uint2* __restrict__ brw, int E, int CE) {
  __shared__ int cur[8];
  int bid = blockIdx.x;
  int c = bid >> 2, q = bid & 3;
  int t = threadIdx.x;
  if (t < 8) cur[t] = boff[(c * 8 + t) * 4 + q];
  __syncthreads();
  int e0 = c * CE, e1 = min(E, e0 + CE);
  int S = (CE + 3) >> 2;
  int s0 = e0 + q * S, s1 = min(e1, s0 + S);
  for (int e = s0 + t; e < s1; e += 1024) {
    int b = col[e];
    int r = b / BPR;
    int pos = atomicAdd(&cur[r], 1);
    bloc[pos] = (unsigned short)(b - r * BPR);
    brw[pos] = make_uint2((unsigned)row[e], __float_as_uint(w[e]));
  }
}

// ------- histogram + weighted-degree from bucket data ----------------
__global__ __launch_bounds__(1024) void k_hist2(const unsigned short* __restrict__ bloc,
                                                const uint2* __restrict__ brw,
                                                const int* __restrict__ boff,
                                                unsigned* __restrict__ partial,
                                                float* __restrict__ wdeg,
                                                int N, int ranges) {
  __shared__ unsigned lds[WPR];
  __shared__ float swdeg[BPR];
  int r = blockIdx.x % ranges;
  int c = blockIdx.x / ranges;
  int t = threadIdx.x;
  for (int i = t; i < WPR; i += 1024) lds[i] = 0;
  for (int i = t; i < BPR; i += 1024) swdeg[i] = 0.f;
  __syncthreads();
  int s0 = boff[(c * 8 + r) * 4], s1 = boff[(c * 8 + r) * 4 + 4];
  for (int i = s0 + t; i < s1; i += 1024) {
    int local = bloc[i];
    float wv = __uint_as_float(brw[i].y);
    atomicAdd(&lds[local >> 1], 1u << (16 * (local & 1)));
    atomicAdd(&swdeg[local], wv);
  }
  __syncthreads();
  unsigned* dst = partial + ((size_t)r * CHUNKS + c) * WPR;
  for (int i = t; i < WPR; i += 1024) dst[i] = lds[i];
  int lo = r * BPR;
  int hi = min(N, lo + BPR);
  for (int i = lo + t; i < hi; i += 1024) {
    float v = swdeg[i - lo];
    if (v != 0.f) atomicAdd(&wdeg[i], v);
  }
}

// ---------------- per-bin prefix over chunks (+ fused dinv) ----------------
__global__ void k_colprefix(const unsigned* __restrict__ partial,
                            unsigned short* __restrict__ rel,
                            int* __restrict__ cnt, const float* __restrict__ wdeg,
                            float* __restrict__ dinv, int N, int npad) {
  int bin = blockIdx.x * blockDim.x + threadIdx.x;
  if (bin >= N) return;
  int r = bin / BPR, local = bin % BPR;
  int word = local >> 1, sh = 16 * (local & 1);
  const unsigned* p = partial + (size_t)r * CHUNKS * WPR + word;
  unsigned acc = 0;
  for (int c = 0; c < CHUNKS; c++) {
    unsigned v = (p[(size_t)c * WPR] >> sh) & 0xFFFFu;
    rel[(size_t)c * npad + bin] = (unsigned short)acc;
    acc += v;
  }
  cnt[bin] = (int)acc;
  dinv[bin] = rsqrtf(1.0f + wdeg[bin]);
}

// ---------------- exclusive scan of cnt -> offs ----------------
__global__ void k_scan1(const int* __restrict__ cnt, int* __restrict__ offs,
                        int* __restrict__ bsum, int n) {
  __shared__ int s[1024];
  int tid = threadIdx.x;
  int i = blockIdx.x * 1024 + tid;
  int v = (i < n) ? cnt[i] : 0;
  s[tid] = v;
  __syncthreads();
  for (int d = 1; d < 1024; d <<= 1) {
    int t = (tid >= d) ? s[tid - d] : 0;
    __syncthreads();
    s[tid] += t;
    __syncthreads();
  }
  if (i < n) offs[i] = s[tid] - v;
  if (tid == 1023) bsum[blockIdx.x] = s[1023];
}

__global__ void k_scan2(int* __restrict__ bsum, int nb) {
  __shared__ int s[256];
  __shared__ int carry;
  int t = threadIdx.x;
  if (t == 0) carry = 0;
  __syncthreads();
  for (int base = 0; base < nb; base += 256) {
    int v = (base + t < nb) ? bsum[base + t] : 0;
    s[t] = v;
    __syncthreads();
    for (int d = 1; d < 256; d <<= 1) {
      int x = (t >= d) ? s[t - d] : 0;
      __syncthreads();
      s[t] += x;
      __syncthreads();
    }
    int total = s[255];
    if (base + t < nb) bsum[base + t] = carry + s[t] - v;
    __syncthreads();
    if (t == 0) carry += total;
    __syncthreads();
  }
}

__global__ void k_scan3(int* __restrict__ offs, const int* __restrict__ bsum,
                        int n, int total) {
  int i = blockIdx.x * 1024 + threadIdx.x;
  if (i < n) offs[i] += bsum[blockIdx.x];
  if (i == 0) offs[n] = total;
}

// --- CSR fill from buckets; pack local<<17 | src; y = dinv[src]*w ----
__global__ __launch_bounds__(1024) void k_fill2(const unsigned short* __restrict__ bloc,
                                                const uint2* __restrict__ brw,
                                                const int* __restrict__ boff,
                                                const int* __restrict__ offs,
                                                const unsigned short* __restrict__ rel,
                                                const float* __restrict__ dinv,
                                                uint2* __restrict__ csr8,
                                                int N, int npad, int ranges) {
  __shared__ unsigned cur[WPR];
  int r = blockIdx.x % ranges;
  int c = blockIdx.x / ranges;
  int lo = r * BPR;
  int hi = min(N, lo + BPR);
  int t = threadIdx.x;
  const unsigned* rsrc = (const unsigned*)(rel + (size_t)c * npad + lo);
  int nw = (hi - lo + 1) >> 1;
  for (int i = t; i < nw; i += 1024) cur[i] = rsrc[i];
  __syncthreads();
  int s0 = boff[(c * 8 + r) * 4], s1 = boff[(c * 8 + r) * 4 + 4];
  for (int i = s0 + t; i < s1; i += 1024) {
    int local = bloc[i];
    int sh = 16 * (local & 1);
    unsigned old = atomicAdd(&cur[local >> 1], 1u << sh);
    unsigned myrel = (old >> sh) & 0xFFFFu;
    int pos = offs[lo + local] + (int)myrel;
    uint2 b = brw[i];
    float nm = dinv[b.x] * __uint_as_float(b.y);
    csr8[pos] = make_uint2(b.x | ((unsigned)local << 17), __float_as_uint(nm));
  }
}

// ------- edge-parallel layer-1: segmented-reduce + W1 MLP + BN partials (S,Q,min,max) -----
__global__ __launch_bounds__(256) void k_agg1e(const unsigned short* __restrict__ x16b,
                                               const int* __restrict__ offs,
                                               const uint2* __restrict__ csr8,
                                               const float* __restrict__ dinv,
                                               const float* __restrict__ W1,
                                               const float* __restrict__ b1,
                                               unsigned short* __restrict__ h,
                                               float4* __restrict__ pbn, int N) {
  __shared__ float Ws[F0 * F1];
  __shared__ float bs[F1];
  __shared__ float sacc[NN1 * 16];
  __shared__ unsigned short sx[NN1 * 16];
  __shared__ float sdinv[NN1];
  __shared__ float sS[4][64], sQ[4][64], sMn[4][64], sMx[4][64];
  int t = threadIdx.x;
  int bid = blockIdx.x;
  int n0 = bid * NN1;
  int nn = min(NN1, N - n0);
  int lbase = n0 - (n0 / BPR) * BPR;
  for (int i = t; i < F0 * F1; i += 256) Ws[i] = W1[i];
  if (t < F1) bs[t] = b1[t];
  ((uint2*)sx)[t] = ((const uint2*)(x16b + (size_t)n0 * 16))[t];
  if (t < NN1) sdinv[t] = (t < nn) ? dinv[n0 + t] : 0.f;
  for (int i = t; i < NN1 * 16; i += 256) sacc[i] = 0.f;
  __syncthreads();
  int ebase = offs[n0], eend = offs[n0 + nn];
  int slot = t >> 4, f = t & 15;
  int nsub = (eend - ebase + 15) >> 4;
  int gs = ebase + slot * nsub;
  int ge = min(eend, gs + nsub);
  float sum = 0.f;
  int cid = -1;
  int e = gs;
  for (; e + 4 <= ge; e += 4) {
    uint2 v0 = csr8[e], v1 = csr8[e + 1], v2 = csr8[e + 2], v3 = csr8[e + 3];
    int i0 = (int)(v0.x >> 17) - lbase, i1 = (int)(v1.x >> 17) - lbase;
    int i2 = (int)(v2.x >> 17) - lbase, i3 = (int)(v3.x >> 17) - lbase;
    float c0 = __uint_as_float(v0.y) * bf2f(x16b[(size_t)(v0.x & 0x1FFFFu) * 16 + f]);
    float c1 = __uint_as_float(v1.y) * bf2f(x16b[(size_t)(v1.x & 0x1FFFFu) * 16 + f]);
    float c2 = __uint_as_float(v2.y) * bf2f(x16b[(size_t)(v2.x & 0x1FFFFu) * 16 + f]);
    float c3 = __uint_as_float(v3.y) * bf2f(x16b[(size_t)(v3.x & 0x1FFFFu) * 16 + f]);
    bool sm;
    sm = (i0 == cid); if (!sm && cid >= 0) atomicAdd(&sacc[cid * 16 + f], sum);
    sum = sm ? sum + c0 : c0; cid = i0;
    sm = (i1 == cid); if (!sm) atomicAdd(&sacc[cid * 16 + f], sum);
    sum = sm ? sum + c1 : c1; cid = i1;
    sm = (i2 == cid); if (!sm) atomicAdd(&sacc[cid * 16 + f], sum);
    sum = sm ? sum + c2 : c2; cid = i2;
    sm = (i3 == cid); if (!sm) atomicAdd(&sacc[cid * 16 + f], sum);
    sum = sm ? sum + c3 : c3; cid = i3;
  }
  for (; e < ge; e++) {
    uint2 v0 = csr8[e];
    int i0 = (int)(v0.x >> 17) - lbase;
    float c0 = __uint_as_float(v0.y) * bf2f(x16b[(size_t)(v0.x & 0x1FFFFu) * 16 + f]);
    bool sm = (i0 == cid);
    if (!sm && cid >= 0) atomicAdd(&sacc[cid * 16 + f], sum);
    sum = sm ? sum + c0 : c0; cid = i0;
  }
  if (cid >= 0) atomicAdd(&sacc[cid * 16 + f], sum);
  __syncthreads();
  for (int i = t; i < NN1 * 16; i += 256) {
    float di = sdinv[i >> 4];
    sacc[i] = di * (sacc[i] + di * bf2f(sx[i]));
  }
  __syncthreads();
  int ff = t & 63, wv = t >> 6;
  float S = 0.f, Q = 0.f, Mn = 1e30f, Mx = -1e30f;
  for (int i = 0; i < 16; i++) {
    int nd = wv + 4 * i;
    if (nd < nn) {
      float o = bs[ff];
#pragma unroll
      for (int k = 0; k < F0; k++) o += sacc[nd * 16 + k] * Ws[k * F1 + ff];
      h[(size_t)(n0 + nd) * F1 + ff] = f2bf(o);
      S += o; Q += o * o;
      Mn = fminf(Mn, o); Mx = fmaxf(Mx, o);
    }
  }
  sS[wv][ff] = S; sQ[wv][ff] = Q; sMn[wv][ff] = Mn; sMx[wv][ff] = Mx;
  __syncthreads();
  if (t < 64)
    pbn[(size_t)bid * 64 + t] = make_float4(
        sS[0][t] + sS[1][t] + sS[2][t] + sS[3][t],
        sQ[0][t] + sQ[1][t] + sQ[2][t] + sQ[3][t],
        fminf(fminf(sMn[0][t], sMn[1][t]), fminf(sMn[2][t], sMn[3][t])),
        fmaxf(fmaxf(sMx[0][t], sMx[1][t]), fmaxf(sMx[2][t], sMx[3][t])));
}

// mid-level BN reduction over nrows partial rows
__global__ void k_bn_mid(const float4* __restrict__ pbn, float4* __restrict__ pbn2, int nrows) {
  __shared__ float sS[4][64], sQ[4][64], sMn[4][64], sMx[4][64];
  int t = threadIdx.x;
  int f = t & 63, g = t >> 6;
  int rpb = (nrows + 63) / 64;
  int b0 = blockIdx.x * rpb;
  int bend = min(nrows, b0 + rpb);
  float S = 0.f, Q = 0.f, Mn = 1e30f, Mx = -1e30f;
  for (int b = b0 + g; b < bend; b += 4) {
    float4 v = pbn[(size_t)b * 64 + f];
    S += v.x; Q += v.y;
    Mn = fminf(Mn, v.z); Mx = fmaxf(Mx, v.w);
  }
  sS[g][f] = S; sQ[g][f] = Q; sMn[g][f] = Mn; sMx[g][f] = Mx;
  __syncthreads();
  if (t < 64)
    pbn2[(size_t)blockIdx.x * 64 + t] = make_float4(
        sS[0][t] + sS[1][t] + sS[2][t] + sS[3][t],
        sQ[0][t] + sQ[1][t] + sQ[2][t] + sQ[3][t],
        fminf(fminf(sMn[0][t], sMn[1][t]), fminf(sMn[2][t], sMn[3][t])),
        fmaxf(fmaxf(sMx[0][t], sMx[1][t]), fmaxf(sMx[2][t], sMx[3][t])));
}

// final: BN affine params + u8 quantization scale (qparams[0]=s_deq, qparams[1]=qscale)
__global__ void k_bn_final(const float4* __restrict__ pbn2, const float* __restrict__ gamma,
                           const float* __restrict__ beta, float* __restrict__ scalef,
                           float* __restrict__ shiftf, float* __restrict__ qparams, int n) {
  __shared__ double sS[4][64], sQ[4][64];
  __shared__ float sMn[4][64], sMx[4][64];
  __shared__ float sM[64];
  int t = threadIdx.x;
  int f = t & 63, g = t >> 6;
  double S = 0.0, Q = 0.0;
  float Mn = 1e30f, Mx = -1e30f;
  for (int b = g; b < 64; b += 4) {
    float4 v = pbn2[(size_t)b * 64 + f];
    S += v.x; Q += v.y;
    Mn = fminf(Mn, v.z); Mx = fmaxf(Mx, v.w);
  }
  sS[g][f] = S; sQ[g][f] = Q; sMn[g][f] = Mn; sMx[g][f] = Mx;
  __syncthreads();
  if (t < 64) {
    double SS = sS[0][t] + sS[1][t] + sS[2][t] + sS[3][t];
    double QQ = sQ[0][t] + sQ[1][t] + sQ[2][t] + sQ[3][t];
    float mn = fminf(fminf(sMn[0][t], sMn[1][t]), fminf(sMn[2][t], sMn[3][t]));
    float mx = fmaxf(fmaxf(sMx[0][t], sMx[1][t]), fmaxf(sMx[2][t], sMx[3][t]));
    double mean = SS / (double)n;
    double var = QQ / (double)n - mean * mean;
    if (var < 0.0) var = 0.0;
    float scale = gamma[t] * (float)(1.0 / sqrt(var + 1e-5));
    float shift = beta[t] - (float)mean * scale;
    scalef[t] = scale;
    shiftf[t] = shift;
    float hi = fmaxf(fmaxf(scale * mx + shift, scale * mn + shift), 0.f);
    sM[t] = hi;   // per-feature max of relu(bn(h))
  }
  __syncthreads();
  if (t == 0) {
    float M = 0.f;
    for (int i = 0; i < 64; i++) M = fmaxf(M, sM[i]);
    float qs = (M > 1e-20f) ? 255.0f / M : 0.f;
    qparams[0] = (M > 1e-20f) ? M / 255.0f : 0.f;   // dequant scale
    qparams[1] = qs;                                // quant scale
  }
}

// ---------------- hn8 = u8(relu(bn(h)) * qscale) elementwise ----------------
__global__ void k_hn(const unsigned short* __restrict__ h, const float* __restrict__ scalef,
                     const float* __restrict__ shiftf, const float* __restrict__ qparams,
                     unsigned char* __restrict__ hn8, int total4) {
  __shared__ float ssc[64], ssf[64];
  int t = threadIdx.x;
  if (t < 64) { ssc[t] = scalef[t]; ssf[t] = shiftf[t]; }
  __syncthreads();
  float qs = qparams[1];
  int idx = blockIdx.x * blockDim.x + t;
  int stride = gridDim.x * blockDim.x;
  const unsigned long long* hp = (const unsigned long long*)h;
  unsigned* hnp = (unsigned*)hn8;
  for (int i = idx; i < total4; i += stride) {
    unsigned long long vv = hp[i];
    int f0 = (i * 4) & 63;
    float a = fmaxf(fmaf(bf2f_lo((unsigned)vv), ssc[f0 + 0], ssf[f0 + 0]), 0.f);
    float b = fmaxf(fmaf(bf2f_hi((unsigned)vv), ssc[f0 + 1], ssf[f0 + 1]), 0.f);
    float c = fmaxf(fmaf(bf2f_lo((unsigned)(vv >> 32)), ssc[f0 + 2], ssf[f0 + 2]), 0.f);
    float d = fmaxf(fmaf(bf2f_hi((unsigned)(vv >> 32)), ssc[f0 + 3], ssf[f0 + 3]), 0.f);
    unsigned ua = min(255u, (unsigned)(a * qs + 0.5f));
    unsigned ub = min(255u, (unsigned)(b * qs + 0.5f));
    unsigned uc = min(255u, (unsigned)(c * qs + 0.5f));
    unsigned ud = min(255u, (unsigned)(d * qs + 0.5f));
    hnp[i] = ua | (ub << 8) | (uc << 16) | (ud << 24);
  }
}

// -------- layer-2 aggregation: wave-per-node, 8 chains, u8 gathers, bf16 output --------
__global__ void k_agg2(const unsigned char* __restrict__ hn8, const int* __restrict__ offs,
                       const uint2* __restrict__ csr8, const float* __restrict__ dinv,
                       const float* __restrict__ qparams,
                       unsigned short* __restrict__ agg2b, int n) {
  __shared__ unsigned s_soff[4][64];
  __shared__ float    s_nrm[4][64];
  int t = threadIdx.x;
  int wv = t >> 6;
  int lane = t & 63;
  int wid = (blockIdx.x * blockDim.x + t) >> 6;
  if (wid >= n) return;
  float sd = qparams[0];   // dequant scale, folded into norms
  float di = dinv[wid];
  float a0 = di * sd * (float)hn8[(size_t)wid * F1 + lane];   // self loop
  float a1 = 0.f, a2 = 0.f, a3 = 0.f, a4 = 0.f, a5 = 0.f, a6 = 0.f, a7 = 0.f;
  int s = offs[wid], e = offs[wid + 1];
  for (int base = s; base < e; base += 64) {
    int m = e - base; if (m > 64) m = 64;
    if (lane < m) {
      uint2 v = csr8[base + lane];
      s_soff[wv][lane] = (v.x & 0x1FFFFu) * 64u;
      s_nrm[wv][lane] = sd * __uint_as_float(v.y);
    } else {
      s_soff[wv][lane] = 0u;
      s_nrm[wv][lane] = 0.f;
    }
    int mp = (m + 7) & ~7;
    for (int j = 0; j < mp; j += 8) {
      unsigned o0 = s_soff[wv][j + 0], o1 = s_soff[wv][j + 1];
      unsigned o2 = s_soff[wv][j + 2], o3 = s_soff[wv][j + 3];
      unsigned o4 = s_soff[wv][j + 4], o5 = s_soff[wv][j + 5];
      unsigned o6 = s_soff[wv][j + 6], o7 = s_soff[wv][j + 7];
      float m0 = s_nrm[wv][j + 0], m1 = s_nrm[wv][j + 1];
      float m2 = s_nrm[wv][j + 2], m3 = s_nrm[wv][j + 3];
      float m4 = s_nrm[wv][j + 4], m5 = s_nrm[wv][j + 5];
      float m6 = s_nrm[wv][j + 6], m7 = s_nrm[wv][j + 7];
      a0 += m0 * (float)hn8[(size_t)o0 + lane];
      a1 += m1 * (float)hn8[(size_t)o1 + lane];
      a2 += m2 * (float)hn8[(size_t)o2 + lane];
      a3 += m3 * (float)hn8[(size_t)o3 + lane];
      a4 += m4 * (float)hn8[(size_t)o4 + lane];
      a5 += m5 * (float)hn8[(size_t)o5 + lane];
      a6 += m6 * (float)hn8[(size_t)o6 + lane];
      a7 += m7 * (float)hn8[(size_t)o7 + lane];
    }
  }
  float r = di * (((a0 + a1) + (a2 + a3)) + ((a4 + a5) + (a6 + a7)));
  agg2b[(size_t)wid * F1 + lane] = f2bf(r);
}

// ---------------- out = agg2b(bf16) @ W2 + b2, register-tiled GEMM ----------------
__global__ __launch_bounds__(256) void k_gemm2(const unsigned short* __restrict__ agg2b,
                                               const float* __restrict__ W2,
                                               const float* __restrict__ b2,
                                               float* __restrict__ out, int n) {
  __shared__ float Ws[F1 * F2];
  __shared__ float As[F1][TN2];
  int t = threadIdx.x;
  for (int i = t; i < F1 * F2 / 4; i += 256) ((float4*)Ws)[i] = ((const float4*)W2)[i];
  int nb = blockIdx.x * TN2;
  int node = t & 127;
  int kh = (t >> 7) * 32;
  int gnode = nb + node;
  if (gnode < n) {
    const uint4* src = (const uint4*)(agg2b + (size_t)gnode * F1 + kh);
#pragma unroll
    for (int j = 0; j < 4; j++) {
      uint4 v = src[j];
      As[kh + j * 8 + 0][node] = bf2f_lo(v.x);
      As[kh + j * 8 + 1][node] = bf2f_hi(v.x);
      As[kh + j * 8 + 2][node] = bf2f_lo(v.y);
      As[kh + j * 8 + 3][node] = bf2f_hi(v.y);
      As[kh + j * 8 + 4][node] = bf2f_lo(v.z);
      As[kh + j * 8 + 5][node] = bf2f_hi(v.z);
      As[kh + j * 8 + 6][node] = bf2f_lo(v.w);
      As[kh + j * 8 + 7][node] = bf2f_hi(v.w);
    }
  } else {
#pragma unroll
    for (int j = 0; j < 8; j++) {
      As[kh + j * 4 + 0][node] = 0.f;
      As[kh + j * 4 + 1][node] = 0.f;
      As[kh + j * 4 + 2][node] = 0.f;
      As[kh + j * 4 + 3][node] = 0.f;
    }
  }
  __syncthreads();

  int f0 = (t & 15) * 8;
  int n0 = (t >> 4) * 8;
  float acc[8][8];
  float bv[8];
#pragma unroll
  for (int j = 0; j < 8; j++) bv[j] = b2[f0 + j];
#pragma unroll
  for (int i = 0; i < 8; i++)
#pragma unroll
    for (int j = 0; j < 8; j++) acc[i][j] = bv[j];

#pragma unroll 4
  for (int k = 0; k < F1; k++) {
    float4 a0 = *(const float4*)&As[k][n0];
    float4 a1 = *(const float4*)&As[k][n0 + 4];
    float4 w0 = *(const float4*)&Ws[k * F2 + f0];
    float4 w1 = *(const float4*)&Ws[k * F2 + f0 + 4];
    float a[8] = {a0.x, a0.y, a0.z, a0.w, a1.x, a1.y, a1.z, a1.w};
    float w[8] = {w0.x, w0.y, w0.z, w0.w, w1.x, w1.y, w1.z, w1.w};
#pragma unroll
    for (int i = 0; i < 8; i++)
#pragma unroll
      for (int j = 0; j < 8; j++) acc[i][j] += a[i] * w[j];
  }

#pragma unroll
  for (int i = 0; i < 8; i++) {
    int gi = nb + n0 + i;
    if (gi < n) {
      float4 o0 = {acc[i][0], acc[i][1], acc[i][2], acc[i][3]};
      float4 o1 = {acc[i][4], acc[i][5], acc[i][6], acc[i][7]};
      *(float4*)&out[(size_t)gi * F2 + f0] = o0;
      *(float4*)&out[(size_t)gi * F2 + f0 + 4] = o1;
    }
  }
}

extern "C" void kernel_launch(void* const* d_in, const int* in_sizes, int n_in,
                              void* d_out, int out_size, void* d_ws, size_t ws_size,
                              hipStream_t stream) {
  const float* x     = (const float*)d_in[0];
  const int*   ei    = (const int*)d_in[1];
  const float* ew    = (const float*)d_in[2];
  const float* W1    = (const float*)d_in[3];
  const float* b1    = (const float*)d_in[4];
  const float* gamma = (const float*)d_in[5];
  const float* beta  = (const float*)d_in[6];
  const float* W2    = (const float*)d_in[7];
  const float* b2    = (const float*)d_in[8];
  float* out = (float*)d_out;

  int N = in_sizes[0] / F0;
  int E = in_sizes[1] / 2;
  const int* row = ei;
  const int* col = ei + E;
  if (N <= 0) return;

  int CE = (E + CHUNKS - 1) / CHUNKS;
  int RANGES = (N + BPR - 1) / BPR;
  int npad = RANGES * BPR;
  int NBLK = (N + NN1 - 1) / NN1;

  // ---- workspace carve-up (with overlays) ----
  char* p = (char*)d_ws;
  auto alloc = [&](size_t bytes) -> void* {
    void* r = (void*)p;
    p += (bytes + 255) & ~(size_t)255;
    return r;
  };
  size_t partial_bytes = ((size_t)RANGES * CHUNKS * WPR * 4 + 255) & ~(size_t)255;
  size_t rel_bytes     = (size_t)CHUNKS * npad * 2;
  size_t h_bytes       = (size_t)N * F1 * 2;
  size_t region_bytes  = partial_bytes + rel_bytes;
  if (h_bytes > region_bytes) region_bytes = h_bytes;

  float*          dinv    = (float*)alloc((size_t)N * 4);
  float*          wdeg    = (float*)alloc((size_t)N * 4);
  int*            cnt     = (int*)alloc((size_t)N * 4);
  int*            offs    = (int*)alloc((size_t)(N + 1) * 4);
  int             NB      = (N + 1023) / 1024;
  int*            bsum    = (int*)alloc((size_t)NB * 4);
  uint2*          csr8    = (uint2*)alloc((size_t)E * 8);
  char*           region  = (char*)alloc(region_bytes);
  unsigned*       partial = (unsigned*)region;
  unsigned short* rel     = (unsigned short*)(region + partial_bytes);
  unsigned short* h       = (unsigned short*)region;     // after fill2
  unsigned short* x16b    = (unsigned short*)alloc((size_t)N * 16 * 2);
  unsigned char*  hn8     = (unsigned char*)alloc((size_t)N * F1);
  // bucket region also hosts agg2b afterwards
  size_t bloc_bytes = (((size_t)E * 2) + 255) & ~(size_t)255;
  size_t bkt_bytes  = bloc_bytes + (size_t)E * 8;
  size_t a2b_bytes  = (size_t)N * F1 * 2;
  char*           bktreg  = (char*)alloc(bkt_bytes > a2b_bytes ? bkt_bytes : a2b_bytes);
  unsigned short* bloc    = (unsigned short*)bktreg;
  uint2*          brw     = (uint2*)(bktreg + bloc_bytes);
  unsigned short* agg2b   = (unsigned short*)bktreg;     // after fill2 (buckets dead)
  float4*         pbn     = (float4*)alloc((size_t)NBLK * 64 * 16);
  float4*         pbn2    = (float4*)alloc((size_t)64 * 64 * 16);
  float*          scalef  = (float*)alloc(64 * 4);
  float*          shiftf  = (float*)alloc(64 * 4);
  float*          qparams = (float*)alloc(2 * 4);
  int*            bcnt    = (int*)alloc((size_t)NBKT * 4);
  int*            boff    = (int*)alloc((size_t)(NBKT + 1) * 4);
  (void)ws_size; (void)n_in; (void)out_size;

  int bW  = (N + 3) / 4;
  int bG2 = (N + TN2 - 1) / TN2;
  int gRC = CHUNKS * RANGES;

  k_pad<<<(N * 16 + 255) / 256, 256, 0, stream>>>(x, x16b, wdeg, N);
  k_cnt8<<<CHUNKS * 4, 1024, 0, stream>>>(col, bcnt, E, CE);
  k_scan8<<<1, 1024, 0, stream>>>(bcnt, boff);
  k_scatter<<<CHUNKS * 4, 1024, 0, stream>>>(col, row, ew, boff, bloc, brw, E, CE);
  k_hist2<<<gRC, 1024, 0, stream>>>(bloc, brw, boff, partial, wdeg, N, RANGES);
  k_colprefix<<<(N + 255) / 256, 256, 0, stream>>>(partial, rel, cnt, wdeg, dinv, N, npad);
  k_scan1<<<NB, 1024, 0, stream>>>(cnt, offs, bsum, N);
  k_scan2<<<1, 256, 0, stream>>>(bsum, NB);
  k_scan3<<<NB, 1024, 0, stream>>>(offs, bsum, N, E);
  k_fill2<<<gRC, 1024, 0, stream>>>(bloc, brw, boff, offs, rel, dinv, csr8, N, npad, RANGES);
  k_agg1e<<<NBLK, 256, 0, stream>>>(x16b, offs, csr8, dinv, W1, b1, h, pbn, N);
  k_bn_mid<<<64, 256, 0, stream>>>(pbn, pbn2, NBLK);
  k_bn_final<<<1, 256, 0, stream>>>(pbn2, gamma, beta, scalef, shiftf, qparams, N);
  k_hn<<<2048, 256, 0, stream>>>(h, scalef, shiftf, qparams, hn8, N * F1 / 4);
  k_agg2<<<bW, 256, 0, stream>>>(hn8, offs, csr8, dinv, qparams, agg2b, N);
  k_gemm2<<<bG2, 256, 0, stream>>>(agg2b, W2, b2, out, N);
}